// Round 9
// baseline (1196.114 us; speedup 1.0000x reference)
//
#include <hip/hip_runtime.h>
#include <math.h>

#define N_NODES 50000
#define M_PAD 50048            // 391 * 128
#define NUM_EDGES 800000
#define NG 8
#define HID 256
#define RHD 128
#define NEXP 4
#define OUTD 6
#define NPW 4                  // router nodes per wave (r15 config: 8 regressed, r18)
#define SCAN_BLK 196           // ceil(50000/256)
#define SRS 136                // padded per-node LN row stride (bank-conflict-free groups)

typedef unsigned short bf16_t;
using f32x4  = __attribute__((ext_vector_type(4))) float;
using bf16x8 = __attribute__((ext_vector_type(8))) short;

__device__ __forceinline__ float bf2f(unsigned short u) {
  union { unsigned int i; float f; } v; v.i = ((unsigned int)u) << 16; return v.f;
}
__device__ __forceinline__ unsigned short f2bf(float f) {
  union { float f; unsigned int i; } v; v.f = f;
  unsigned int x = v.i;
  unsigned int r = x + 0x7fffu + ((x >> 16) & 1u);  // RNE
  return (unsigned short)(r >> 16);
}
__device__ __forceinline__ float readlane_f(float v, int lane) {
  return __int_as_float(__builtin_amdgcn_readlane(__float_as_int(v), lane));
}

// async global->LDS, 16B per lane; LDS dest is wave-uniform base + lane*16 (HW rule)
__device__ __forceinline__ void gl_lds16(const bf16_t* g, bf16_t* l) {
  __builtin_amdgcn_global_load_lds(
      (const __attribute__((address_space(1))) unsigned int*)(g),
      (__attribute__((address_space(3))) unsigned int*)(l), 16, 0, 0);
}

// ---------------- zero init ----------------
__global__ void k_zero(int* __restrict__ deg, int* __restrict__ n_cnt,
                       int* __restrict__ e_cnt) {
  int i = blockIdx.x * blockDim.x + threadIdx.x;
  if (i < N_NODES) deg[i] = 0;
  if (i < NG) { n_cnt[i] = 0; e_cnt[i] = 0; }
}

// ---------------- fused node+edge counts ----------------
__global__ void k_count(const int* __restrict__ batch, const int* __restrict__ edge,
                        int* __restrict__ n_cnt, int* __restrict__ e_cnt,
                        int* __restrict__ deg) {
  __shared__ int histn[NG], histe[NG];
  int t = threadIdx.x;
  if (t < NG) { histn[t] = 0; histe[t] = 0; }
  __syncthreads();
  int i = blockIdx.x * blockDim.x + t;
  if (i < N_NODES) atomicAdd(&histn[batch[i]], 1);
  if (i < NUM_EDGES) {
    int s = edge[i];
    int d = edge[NUM_EDGES + i];
    atomicAdd(&histe[batch[s]], 1);
    atomicAdd(&deg[d], 1);
  }
  __syncthreads();
  if (t < NG) {
    if (histn[t]) atomicAdd(&n_cnt[t], histn[t]);
    if (histe[t]) atomicAdd(&e_cnt[t], histe[t]);
  }
}

// numpy-faithful f32 stats (frozen: razor-sensitive)
__device__ __forceinline__ float tree8(const float* v) {
  float s01 = __fadd_rn(v[0], v[1]);
  float s23 = __fadd_rn(v[2], v[3]);
  float s45 = __fadd_rn(v[4], v[5]);
  float s67 = __fadd_rn(v[6], v[7]);
  return __fadd_rn(__fadd_rn(s01, s23), __fadd_rn(s45, s67));
}

__global__ void k_graph_stats(const int* __restrict__ n_cnt, const int* __restrict__ e_cnt,
                              float* __restrict__ gf, float* __restrict__ lnn) {
  if (threadIdx.x != 0 || blockIdx.x != 0) return;
  float logn[NG], loge[NG];
  for (int g = 0; g < NG; ++g) {
    float nf = fmaxf((float)n_cnt[g], 1.0f);
    logn[g] = (float)log((double)nf);
    float ef = fmaxf((float)e_cnt[g], 0.0f);
    loge[g] = (float)log1p((double)ef);
  }
  float m0 = __fdiv_rn(tree8(logn), 8.0f);
  float m1 = __fdiv_rn(tree8(loge), 8.0f);
  float sq0[NG], sq1[NG];
  float mn = 3.0e38f, mx = -3.0e38f;
  for (int g = 0; g < NG; ++g) {
    float d0 = __fsub_rn(logn[g], m0);
    float d1 = __fsub_rn(loge[g], m1);
    sq0[g] = __fmul_rn(d0, d0);
    sq1[g] = __fmul_rn(d1, d1);
    mn = fminf(mn, logn[g]); mx = fmaxf(mx, logn[g]);
  }
  float s0 = __fadd_rn(sqrtf(__fdiv_rn(tree8(sq0), 8.0f)), 1e-6f);
  float s1 = __fadd_rn(sqrtf(__fdiv_rn(tree8(sq1), 8.0f)), 1e-6f);
  float denom = __fadd_rn(__fsub_rn(mx, mn), 1e-6f);
  for (int g = 0; g < NG; ++g) {
    gf[g * 2 + 0] = __fdiv_rn(__fsub_rn(logn[g], m0), s0);
    gf[g * 2 + 1] = __fdiv_rn(__fsub_rn(loge[g], m1), s1);
    lnn[g] = __fdiv_rn(__fsub_rn(logn[g], mn), denom);
  }
}

// ---------------- CSR build: two-level parallel scan ----------------
__global__ void k_scan_a(const int* __restrict__ deg, int* __restrict__ excl,
                         int* __restrict__ bsum) {
  __shared__ int temp[256];
  int b = blockIdx.x, t = threadIdx.x;
  int i = b * 256 + t;
  int v = (i < N_NODES) ? deg[i] : 0;
  temp[t] = v;
  __syncthreads();
  for (int off = 1; off < 256; off <<= 1) {
    int x = (t >= off) ? temp[t - off] : 0;
    __syncthreads();
    temp[t] += x;
    __syncthreads();
  }
  if (i < N_NODES) excl[i] = temp[t] - v;
  if (t == 255) bsum[b] = temp[255];
}

__global__ void k_scan_b(const int* __restrict__ bsum, int* __restrict__ boff,
                         int* __restrict__ row_start) {
  __shared__ int temp[256];
  int t = threadIdx.x;
  int v = (t < SCAN_BLK) ? bsum[t] : 0;
  temp[t] = v;
  __syncthreads();
  for (int off = 1; off < 256; off <<= 1) {
    int x = (t >= off) ? temp[t - off] : 0;
    __syncthreads();
    temp[t] += x;
    __syncthreads();
  }
  if (t < SCAN_BLK) boff[t] = temp[t] - v;
  if (t == SCAN_BLK - 1) row_start[N_NODES] = temp[t];
}

__global__ void k_scan_c(const int* __restrict__ excl, const int* __restrict__ boff,
                         int* __restrict__ row_start, int* __restrict__ cursor) {
  int i = blockIdx.x * 256 + threadIdx.x;
  if (i < N_NODES) {
    int e = excl[i] + boff[blockIdx.x];
    row_start[i] = e;
    cursor[i] = e;
  }
}

__global__ void k_fill(const int* __restrict__ edge, int* __restrict__ cursor,
                       int* __restrict__ csr_src) {
  int i = blockIdx.x * blockDim.x + threadIdx.x;
  if (i < NUM_EDGES) {
    int d = edge[NUM_EDGES + i];
    int p = atomicAdd(&cursor[d], 1);
    csr_src[p] = edge[i];
  }
}

// ---------------- encoder layer 1 (frozen) -----------------------------------------
__global__ void k_enc1(const float* __restrict__ x, const float* __restrict__ w1,
                       const float* __restrict__ b1, float* __restrict__ t) {
  __shared__ float W[6 * 256];
  __shared__ float xs[16][6];
  int tid = threadIdx.x;
  for (int i = tid; i < 6 * 256; i += 256) W[i] = w1[i];
  int base = blockIdx.x * 16;
  if (tid < 96) {
    int n = tid / 6, k = tid % 6;
    int node = base + n;
    xs[n][k] = (node < N_NODES) ? x[node * 16 + 4 + k] : 0.f;
  }
  __syncthreads();
  float b = b1[tid];
  for (int n = 0; n < 16; ++n) {
    int node = base + n;
    if (node >= N_NODES) break;
    float acc = 0.f;
#pragma unroll
    for (int k = 0; k < 6; ++k) acc = __fmaf_rn(xs[n][k], W[k * 256 + tid], acc);
    t[node * 256 + tid] = fmaxf(__fadd_rn(acc, b), 0.f);
  }
}

// ---------------- fp32 SIMT GEMM (frozen math; epilogue also emits bf16 copy) -------
__global__ __launch_bounds__(256, 2) void k_gemm_enc(
    const float* __restrict__ A, const float* __restrict__ W0,
    const float* __restrict__ bias, float* __restrict__ C,
    bf16_t* __restrict__ Cb, int M) {
  __shared__ float As[16][132];
  __shared__ float Ws[16][128];
  const int tid = threadIdx.x;
  const int tx = tid & 15;
  const int ty = tid >> 4;
  const int rowBase = blockIdx.x * 128;
  const int colBase = blockIdx.y * 128;

  float acc[2][2][4][4];
#pragma unroll
  for (int a = 0; a < 2; ++a)
#pragma unroll
    for (int b = 0; b < 2; ++b)
#pragma unroll
      for (int i = 0; i < 4; ++i)
#pragma unroll
        for (int j = 0; j < 4; ++j) acc[a][b][i][j] = 0.f;

  for (int kt = 0; kt < 16; ++kt) {
    const int kb = kt * 16;
#pragma unroll
    for (int l = 0; l < 2; ++l) {
      int idx = tid + l * 256;
      int m = idx >> 2;
      int kq = (idx & 3) * 4;
      int arow = rowBase + m;
      float4 av = make_float4(0.f, 0.f, 0.f, 0.f);
      if (arow < M) av = *reinterpret_cast<const float4*>(&A[arow * 256 + kb + kq]);
      As[kq + 0][m] = av.x; As[kq + 1][m] = av.y;
      As[kq + 2][m] = av.z; As[kq + 3][m] = av.w;
    }
#pragma unroll
    for (int l = 0; l < 2; ++l) {
      int idx = tid + l * 256;
      int k = idx >> 5;
      int nq = (idx & 31) * 4;
      float4 wv = *reinterpret_cast<const float4*>(&W0[(kb + k) * 256 + colBase + nq]);
      *reinterpret_cast<float4*>(&Ws[k][nq]) = wv;
    }
    __syncthreads();
#pragma unroll
    for (int k = 0; k < 16; ++k) {
      float4 a0 = *reinterpret_cast<const float4*>(&As[k][ty * 4]);
      float4 a1 = *reinterpret_cast<const float4*>(&As[k][64 + ty * 4]);
      float4 w0 = *reinterpret_cast<const float4*>(&Ws[k][tx * 4]);
      float4 w1 = *reinterpret_cast<const float4*>(&Ws[k][64 + tx * 4]);
      float ar[2][4] = {{a0.x, a0.y, a0.z, a0.w}, {a1.x, a1.y, a1.z, a1.w}};
      float wr[2][4] = {{w0.x, w0.y, w0.z, w0.w}, {w1.x, w1.y, w1.z, w1.w}};
#pragma unroll
      for (int ri = 0; ri < 2; ++ri)
#pragma unroll
        for (int i = 0; i < 4; ++i)
#pragma unroll
          for (int ci = 0; ci < 2; ++ci)
#pragma unroll
            for (int j = 0; j < 4; ++j)
              acc[ri][ci][i][j] = __fmaf_rn(ar[ri][i], wr[ci][j], acc[ri][ci][i][j]);
    }
    __syncthreads();
  }
  float4 bv0 = *reinterpret_cast<const float4*>(&bias[colBase + tx * 4]);
  float4 bv1 = *reinterpret_cast<const float4*>(&bias[colBase + 64 + tx * 4]);
  float bb[2][4] = {{bv0.x, bv0.y, bv0.z, bv0.w}, {bv1.x, bv1.y, bv1.z, bv1.w}};
#pragma unroll
  for (int ri = 0; ri < 2; ++ri) {
#pragma unroll
    for (int i = 0; i < 4; ++i) {
      int row = rowBase + ri * 64 + ty * 4 + i;
      if (row < M) {
#pragma unroll
        for (int ci = 0; ci < 2; ++ci) {
          float o[4];
#pragma unroll
          for (int j = 0; j < 4; ++j)
            o[j] = __fadd_rn(acc[ri][ci][i][j], bb[ci][j]);
          *reinterpret_cast<float4*>(&C[row * 256 + colBase + ci * 64 + tx * 4]) =
              make_float4(o[0], o[1], o[2], o[3]);
          ushort4 ob = make_ushort4(f2bf(o[0]), f2bf(o[1]), f2bf(o[2]), f2bf(o[3]));
          *reinterpret_cast<ushort4*>(&Cb[(size_t)row * 256 + colBase + ci * 64 + tx * 4]) = ob;
        }
      }
    }
  }
}

// ---------------- weight prep: transpose f32 [k][n] -> bf16 [n][k] ------------------
__global__ void k_wprep(const float* __restrict__ w_rel, const float* __restrict__ w_root,
                        bf16_t* __restrict__ WT) {
  __shared__ bf16_t tile[64][258];
  int m = blockIdx.x;
  int k0 = blockIdx.y * 64;
  const float* src = (m < 8) ? (w_rel + (size_t)m * 65536)
                             : (w_root + (size_t)(m - 8) * 65536);
  bf16_t* dst = WT + (size_t)m * 65536;
  int tid = threadIdx.x;
  for (int r = 0; r < 64; ++r)
    tile[r][tid] = f2bf(src[(k0 + r) * 256 + tid]);
  __syncthreads();
  for (int c = 0; c < 64; c += 8) {
    ushort4 lo, hi;
    lo.x = tile[c + 0][tid]; lo.y = tile[c + 1][tid];
    lo.z = tile[c + 2][tid]; lo.w = tile[c + 3][tid];
    hi.x = tile[c + 4][tid]; hi.y = tile[c + 5][tid];
    hi.z = tile[c + 6][tid]; hi.w = tile[c + 7][tid];
    *reinterpret_cast<ushort4*>(&dst[tid * 256 + k0 + c]) = lo;
    *reinterpret_cast<ushort4*>(&dst[tid * 256 + k0 + c + 4]) = hi;
  }
}

// ---------------- router weight transpose: rtw1[k][128] -> WRT[col][k] (k=0..255) ---
__global__ void k_wrt(const float* __restrict__ rtw1, float* __restrict__ wrt) {
  int c = blockIdx.x;            // 0..127
  int t = threadIdx.x;           // 0..255
  wrt[c * 256 + t] = rtw1[t * RHD + c];
}

// ---------------- MFMA bf16 GEMM core: global_load_lds staging, XOR swizzle ---------
// r8: staging via __builtin_amdgcn_global_load_lds width=16 (no VGPR round-trip, no
// ds_write). LDS LINEAR [row][64] (40 KB -> 4 blocks/CU). Bank conflicts on the
// ds_read_b128 fragment reads fixed by both-sides XOR swizzle (guide §5 #21):
// source 16B-slot ^= (row&7) at stage time, read applies the same XOR.
// Same values, same MFMA order -> BIT-IDENTICAL output. In-place gemm2 safety:
// staging loads drained (vmcnt(0)) by the loop's final __syncthreads() before
// epilogue writes; blocks are row-exclusive (64 rows x all 256 cols).
__device__ __forceinline__ void gemm_core64(
    const bf16_t* __restrict__ A, const bf16_t* __restrict__ W0t,
    const bf16_t* __restrict__ B, const bf16_t* __restrict__ W1t,
    const float* __restrict__ bias, bf16_t* __restrict__ C, int rowBase) {
  __shared__ bf16_t As[64 * 64];    // 8 KB linear
  __shared__ bf16_t Bs[256 * 64];   // 32 KB linear
  const int tid = threadIdx.x;
  const int lane = tid & 63;
  const int wave = tid >> 6;
  const int lm = lane & 15;
  const int quad = lane >> 4;
  const int wn = wave * 64;        // col strip: 4 waves cover 256 cols
  const int lrow = lane >> 3;      // row within an 8-row / 1KB segment
  const int lslot = lane & 7;      // 16B slot within 128B row

  f32x4 acc[4][4];
#pragma unroll
  for (int i = 0; i < 4; ++i)
#pragma unroll
    for (int j = 0; j < 4; ++j) acc[i][j] = (f32x4){0.f, 0.f, 0.f, 0.f};

#pragma unroll
  for (int phase = 0; phase < 2; ++phase) {
    const bf16_t* __restrict__ Ain = phase ? B : A;
    const bf16_t* __restrict__ Wt  = phase ? W1t : W0t;
    for (int kc = 0; kc < 4; ++kc) {          // K-chunks of 64
      const int kb = kc * 64;
#pragma unroll
      for (int l = 0; l < 2; ++l) {
        int s = wave * 2 + l;
        int row = s * 8 + lrow;
        int srcc = kb + ((lslot ^ (row & 7)) << 3);
        gl_lds16(&Ain[(size_t)(rowBase + row) * 256 + srcc], &As[s * 512]);
      }
#pragma unroll
      for (int l = 0; l < 8; ++l) {
        int s = wave * 8 + l;
        int row = s * 8 + lrow;
        int srcc = kb + ((lslot ^ (row & 7)) << 3);
        gl_lds16(&Wt[(size_t)row * 256 + srcc], &Bs[s * 512]);
      }
      __syncthreads();   // drains vmcnt(0): staged data visible
#pragma unroll
      for (int k2 = 0; k2 < 2; ++k2) {        // two K=32 sub-steps
        const int c0 = k2 * 32 + quad * 8;
        bf16x8 af[4], bfr[4];
#pragma unroll
        for (int i = 0; i < 4; ++i) {
          int ar = i * 16 + lm;
          af[i] = *reinterpret_cast<const bf16x8*>(&As[ar * 64 + (c0 ^ ((ar & 7) << 3))]);
        }
#pragma unroll
        for (int j = 0; j < 4; ++j) {
          int br = wn + j * 16 + lm;
          bfr[j] = *reinterpret_cast<const bf16x8*>(&Bs[br * 64 + (c0 ^ ((br & 7) << 3))]);
        }
#pragma unroll
        for (int i = 0; i < 4; ++i)
#pragma unroll
          for (int j = 0; j < 4; ++j)
            acc[i][j] = __builtin_amdgcn_mfma_f32_16x16x32_bf16(af[i], bfr[j], acc[i][j], 0, 0, 0);
      }
      __syncthreads();   // LDS reuse next chunk; final one guards in-place epilogue
    }
  }
  float bj[4];
#pragma unroll
  for (int j = 0; j < 4; ++j) bj[j] = bias[wn + j * 16 + lm];
#pragma unroll
  for (int i = 0; i < 4; ++i) {
#pragma unroll
    for (int j = 0; j < 4; ++j) {
      int col = wn + j * 16 + lm;
#pragma unroll
      for (int r = 0; r < 4; ++r) {
        int row = rowBase + i * 16 + quad * 4 + r;
        C[(size_t)row * 256 + col] = f2bf(fmaxf(acc[i][j][r] + bj[j], 0.f));
      }
    }
  }
}

// pair-batched GEMM1: X1[slot] = relu(AGG@wr0_e + hb@wo0_e + br0_e), e = pe + slot
__global__ __launch_bounds__(256, 4) void k_gemm1_b(
    const bf16_t* __restrict__ AGG, const bf16_t* __restrict__ hb,
    const bf16_t* __restrict__ WT, const float* __restrict__ b_rel,
    bf16_t* __restrict__ X1p, int pe) {
  int slot = blockIdx.y, e = pe + slot;
  gemm_core64(AGG, WT + (size_t)(e * 2) * 65536,
              hb, WT + (size_t)(8 + e * 2) * 65536,
              b_rel + (size_t)(e * 2) * 256,
              X1p + (size_t)slot * M_PAD * 256, blockIdx.x * 64);
}

// pair-batched GEMM2 (in-place; row-exclusive blocks + pre-write barrier make it safe)
__global__ __launch_bounds__(256, 4) void k_gemm2_b(
    const bf16_t* __restrict__ A1p, bf16_t* __restrict__ X1p,
    const bf16_t* __restrict__ WT, const float* __restrict__ b_rel, int pe) {
  int slot = blockIdx.y, e = pe + slot;
  bf16_t* Xs = X1p + (size_t)slot * M_PAD * 256;
  gemm_core64(A1p + (size_t)slot * M_PAD * 256, WT + (size_t)(e * 2 + 1) * 65536,
              Xs, WT + (size_t)(8 + e * 2 + 1) * 65536,
              b_rel + (size_t)(e * 2 + 1) * 256, Xs, blockIdx.x * 64);
}

// ---------------- CSR gather, bf16 in/out (f32 accumulate, unroll-4) ----------------
// At its L3-path floor (~106us, invariant to ILP/TLP changes r1..r8) — frozen.
__device__ __forceinline__ void gather_core(
    const int* __restrict__ row_start, const int* __restrict__ csr_src,
    const bf16_t* __restrict__ X, bf16_t* __restrict__ Cout) {
  int tid = threadIdx.x;
  int r = blockIdx.x * 8 + (tid >> 5);
  int f = (tid & 31) * 8;
  int j0 = row_start[r], j1 = row_start[r + 1];
  float a[8] = {0.f, 0.f, 0.f, 0.f, 0.f, 0.f, 0.f, 0.f};
  int j = j0;
  for (; j + 3 < j1; j += 4) {
    int s0 = csr_src[j];
    int s1 = csr_src[j + 1];
    int s2 = csr_src[j + 2];
    int s3 = csr_src[j + 3];
    bf16x8 v0 = *reinterpret_cast<const bf16x8*>(&X[(size_t)s0 * 256 + f]);
    bf16x8 v1 = *reinterpret_cast<const bf16x8*>(&X[(size_t)s1 * 256 + f]);
    bf16x8 v2 = *reinterpret_cast<const bf16x8*>(&X[(size_t)s2 * 256 + f]);
    bf16x8 v3 = *reinterpret_cast<const bf16x8*>(&X[(size_t)s3 * 256 + f]);
#pragma unroll
    for (int t = 0; t < 8; ++t) a[t] += bf2f((unsigned short)v0[t]);
#pragma unroll
    for (int t = 0; t < 8; ++t) a[t] += bf2f((unsigned short)v1[t]);
#pragma unroll
    for (int t = 0; t < 8; ++t) a[t] += bf2f((unsigned short)v2[t]);
#pragma unroll
    for (int t = 0; t < 8; ++t) a[t] += bf2f((unsigned short)v3[t]);
  }
  for (; j < j1; ++j) {
    int s = csr_src[j];
    bf16x8 v = *reinterpret_cast<const bf16x8*>(&X[(size_t)s * 256 + f]);
#pragma unroll
    for (int t = 0; t < 8; ++t) a[t] += bf2f((unsigned short)v[t]);
  }
  ushort4 lo = make_ushort4(f2bf(a[0]), f2bf(a[1]), f2bf(a[2]), f2bf(a[3]));
  ushort4 hi = make_ushort4(f2bf(a[4]), f2bf(a[5]), f2bf(a[6]), f2bf(a[7]));
  *reinterpret_cast<ushort4*>(&Cout[(size_t)r * 256 + f]) = lo;
  *reinterpret_cast<ushort4*>(&Cout[(size_t)r * 256 + f + 4]) = hi;
}

__global__ void k_gather(const int* __restrict__ row_start, const int* __restrict__ csr_src,
                         const bf16_t* __restrict__ X, bf16_t* __restrict__ Cout) {
  gather_core(row_start, csr_src, X, Cout);
}

__global__ void k_gather_b(const int* __restrict__ row_start, const int* __restrict__ csr_src,
                           const bf16_t* __restrict__ X1p, bf16_t* __restrict__ A1p) {
  size_t off = (size_t)blockIdx.y * M_PAD * 256;
  gather_core(row_start, csr_src, X1p + off, A1p + off);
}

// ---------------- numpy-faithful f32 router -----------------------------------------
// r9: main-loop weight loads vectorized via one-time transposed WRT[col][k] — each
// lane loads float4 of 4 consecutive k (was 2 scalar loads/k at 512B lane stride).
// FMA chain per accumulator stays k-ascending -> BIT-IDENTICAL. All other phases
// (stats read, LN reductions, head, softmax) unchanged from r8.
__global__ __launch_bounds__(256) void k_router_np(
    const float* __restrict__ h, const int* __restrict__ batch,
    const float* __restrict__ gf, const float* __restrict__ lnn,
    const float* __restrict__ wrt, const float* __restrict__ rtw1,
    const float* __restrict__ rtb1,
    const float* __restrict__ lng, const float* __restrict__ lnb,
    const float* __restrict__ rtw2, const float* __restrict__ rtb2,
    const float* __restrict__ centers, float* __restrict__ sw) {
  __shared__ float smem[4][1104];
  const int tid = threadIdx.x;
  const int w = tid >> 6;
  const int l = tid & 63;
  const int nbase = blockIdx.x * (4 * NPW) + w * NPW;   // grid = 3125, exact
  float* sm = smem[w];

  // stage h transposed: hT[k][nn], conflict-free b128 writes (16B lane stride)
#pragma unroll
  for (int j = 0; j < 4; ++j) {
    f32x4 v;
#pragma unroll
    for (int nn = 0; nn < NPW; ++nn)
      v[nn] = h[(size_t)(nbase + nn) * 256 + j * 64 + l];
    *reinterpret_cast<f32x4*>(&sm[(j * 64 + l) * 4]) = v;
  }
  __syncthreads();

  float acc0[NPW], acc1[NPW];
#pragma unroll
  for (int nn = 0; nn < NPW; ++nn) { acc0[nn] = 0.f; acc1[nn] = 0.f; }
#pragma unroll
  for (int j = 0; j < 4; ++j) {
#pragma unroll 4
    for (int k4 = 0; k4 < 16; ++k4) {
      int k = j * 64 + k4 * 4;
      f32x4 w0 = *reinterpret_cast<const f32x4*>(&wrt[(size_t)l * 256 + k]);
      f32x4 w1 = *reinterpret_cast<const f32x4*>(&wrt[(size_t)(l + 64) * 256 + k]);
#pragma unroll
      for (int kk = 0; kk < 4; ++kk) {
        f32x4 hv = *reinterpret_cast<const f32x4*>(&sm[(k + kk) * 4]);  // uniform bcast
#pragma unroll
        for (int nn = 0; nn < NPW; ++nn) {
          acc0[nn] = __fmaf_rn(hv[nn], w0[kk], acc0[nn]);
          acc1[nn] = __fmaf_rn(hv[nn], w1[kk], acc1[nn]);
        }
      }
    }
  }

  float g0a = rtw1[256 * RHD + l],      g1a = rtw1[257 * RHD + l];
  float g0b = rtw1[256 * RHD + l + 64], g1b = rtw1[257 * RHD + l + 64];
  float b0 = rtb1[l], b1v = rtb1[l + 64];
  float lga = lng[l], lgb = lng[l + 64];
  float lba = lnb[l], lbb = lnb[l + 64];

  float r0[NPW], r1[NPW];
#pragma unroll
  for (int nn = 0; nn < NPW; ++nn) {
    int node = nbase + nn;
    int g = batch[node];
    float gf0 = gf[g * 2 + 0], gf1 = gf[g * 2 + 1];
    float t0 = acc0[nn], t1 = acc1[nn];
    t0 = __fmaf_rn(gf0, g0a, t0);
    t0 = __fmaf_rn(gf1, g1a, t0);
    t1 = __fmaf_rn(gf0, g0b, t1);
    t1 = __fmaf_rn(gf1, g1b, t1);
    r0[nn] = __fadd_rn(t0, b0);
    r1[nn] = __fadd_rn(t1, b1v);
    sm[nn * SRS + l] = r0[nn];
    sm[nn * SRS + 64 + l] = r1[nn];
  }
  __syncthreads();

  // mean reduction: 32 lanes, 8 per node (same 16-term ascending chain per sub-lane)
  float aj = 0.f;
  if (l < 32) {
    const float* Sp = &sm[(l >> 3) * SRS];
    int rj = l & 7;
    aj = Sp[rj];
    for (int i = 8; i < 128; i += 8) aj = __fadd_rn(aj, Sp[i + rj]);
  }
  float mu[NPW];
#pragma unroll
  for (int nn = 0; nn < NPW; ++nn) {
    float a0 = __shfl(aj, nn * 8 + 0, 64), a1 = __shfl(aj, nn * 8 + 1, 64);
    float a2 = __shfl(aj, nn * 8 + 2, 64), a3 = __shfl(aj, nn * 8 + 3, 64);
    float a4 = __shfl(aj, nn * 8 + 4, 64), a5 = __shfl(aj, nn * 8 + 5, 64);
    float a6 = __shfl(aj, nn * 8 + 6, 64), a7 = __shfl(aj, nn * 8 + 7, 64);
    float s01 = __fadd_rn(a0, a1), s23 = __fadd_rn(a2, a3);
    float s45 = __fadd_rn(a4, a5), s67 = __fadd_rn(a6, a7);
    float t = __fadd_rn(__fadd_rn(s01, s23), __fadd_rn(s45, s67));
    mu[nn] = __fdiv_rn(t, 128.0f);
  }

  float d0[NPW], d1[NPW];
#pragma unroll
  for (int nn = 0; nn < NPW; ++nn) {
    d0[nn] = __fsub_rn(r0[nn], mu[nn]);
    d1[nn] = __fsub_rn(r1[nn], mu[nn]);
    sm[nn * SRS + l] = __fmul_rn(d0[nn], d0[nn]);
    sm[nn * SRS + 64 + l] = __fmul_rn(d1[nn], d1[nn]);
  }
  __syncthreads();

  // variance reduction (identical chain structure)
  float qj = 0.f;
  if (l < 32) {
    const float* Sp = &sm[(l >> 3) * SRS];
    int rj = l & 7;
    qj = Sp[rj];
    for (int i = 8; i < 128; i += 8) qj = __fadd_rn(qj, Sp[i + rj]);
  }
#pragma unroll
  for (int nn = 0; nn < NPW; ++nn) {
    float a0 = __shfl(qj, nn * 8 + 0, 64), a1 = __shfl(qj, nn * 8 + 1, 64);
    float a2 = __shfl(qj, nn * 8 + 2, 64), a3 = __shfl(qj, nn * 8 + 3, 64);
    float a4 = __shfl(qj, nn * 8 + 4, 64), a5 = __shfl(qj, nn * 8 + 5, 64);
    float a6 = __shfl(qj, nn * 8 + 6, 64), a7 = __shfl(qj, nn * 8 + 7, 64);
    float s01 = __fadd_rn(a0, a1), s23 = __fadd_rn(a2, a3);
    float s45 = __fadd_rn(a4, a5), s67 = __fadd_rn(a6, a7);
    float t = __fadd_rn(__fadd_rn(s01, s23), __fadd_rn(s45, s67));
    float var = __fdiv_rn(t, 128.0f);
    float inv = __fdiv_rn(1.0f, sqrtf(__fadd_rn(var, 1e-5f)));
    float y0 = __fadd_rn(__fmul_rn(__fmul_rn(d0[nn], inv), lga), lba);
    float y1 = __fadd_rn(__fmul_rn(__fmul_rn(d1[nn], inv), lgb), lbb);
    sm[544 + nn * SRS + l] = fmaxf(y0, 0.f);
    sm[544 + nn * SRS + 64 + l] = fmaxf(y1, 0.f);
  }
  __syncthreads();

  // head: 16 lanes = 4 nodes x 4 cols, same serial 128-FMA ascending chain per col
  if (l < 16) {
    int nn = l >> 2, c = l & 3;
    int node = nbase + nn;
    const float* Ap = &sm[544 + nn * SRS];
    float acc = 0.f;
    for (int k = 0; k < 128; ++k) acc = __fmaf_rn(Ap[k], rtw2[k * 4 + c], acc);
    float lrn = __fadd_rn(acc, rtb2[c]);
    float nl = lnn[batch[node]];
    float dd = __fsub_rn(nl, centers[c]);
    float pr = -__fmul_rn(dd, dd);
    sm[1088 + nn * 4 + c] = __fadd_rn(__fmul_rn(0.65f, lrn), __fmul_rn(0.35f, pr));
  }
  __syncthreads();

  // softmax + top2: 4 lanes = 4 nodes (identical code to l==0 path)
  if (l < NPW) {
    int nn = l;
    int node = nbase + nn;
    float lg[4] = {sm[1088 + nn * 4 + 0], sm[1088 + nn * 4 + 1],
                   sm[1088 + nn * 4 + 2], sm[1088 + nn * 4 + 3]};
    float mx = fmaxf(fmaxf(lg[0], lg[1]), fmaxf(lg[2], lg[3]));
    float e[4];
#pragma unroll
    for (int c = 0; c < 4; ++c)
      e[c] = (float)exp((double)__fsub_rn(lg[c], mx));
    float S = __fadd_rn(__fadd_rn(__fadd_rn(e[0], e[1]), e[2]), e[3]);
    float p[4];
#pragma unroll
    for (int c = 0; c < 4; ++c) p[c] = __fdiv_rn(e[c], S);
    int i1 = 0;
#pragma unroll
    for (int c = 1; c < 4; ++c) if (p[c] > p[i1]) i1 = c;
    int i2 = -1;
#pragma unroll
    for (int c = 0; c < 4; ++c) {
      if (c == i1) continue;
      if (i2 < 0 || p[c] > p[i2]) i2 = c;
    }
    float den = __fadd_rn(__fadd_rn(p[i1], p[i2]), 1e-8f);
    float swv[4] = {0.f, 0.f, 0.f, 0.f};
    swv[i1] = __fdiv_rn(p[i1], den);
    swv[i2] = __fdiv_rn(p[i2], den);
    *reinterpret_cast<float4*>(&sw[node * 4]) =
        make_float4(swv[0], swv[1], swv[2], swv[3]);
  }
}

// ---------------- head stage 1 (pair-batched): packed Pp/Qp[n][e*8+c] ---------------
// r9: P (gatherable) and Q (root) now stored e-major packed 32-float rows so the
// headfin gather reads one contiguous 128B row per edge. Same computed values.
__global__ void k_headPQ_b(const bf16_t* __restrict__ X2p,
                           const float* __restrict__ w_relo, const float* __restrict__ w_rooto,
                           float* __restrict__ Pp, float* __restrict__ Qp, int pe) {
  int slot = blockIdx.y, e = pe + slot;
  const bf16_t* X2 = X2p + (size_t)slot * M_PAD * 256;
  const float* wro = w_relo + (size_t)e * 256 * OUTD;
  const float* wto = w_rooto + (size_t)e * 256 * OUTD;
  int tid = threadIdx.x;
  int r = blockIdx.x * 4 + (tid >> 6);    // grid.x = N/4 exact
  int lane = tid & 63;
  int k0 = lane * 4;
  float wr_[24], wt_[24];
#pragma unroll
  for (int q = 0; q < 6; ++q) {
    float4 a = *reinterpret_cast<const float4*>(&wro[k0 * 6 + q * 4]);
    wr_[q * 4 + 0] = a.x; wr_[q * 4 + 1] = a.y; wr_[q * 4 + 2] = a.z; wr_[q * 4 + 3] = a.w;
    float4 b = *reinterpret_cast<const float4*>(&wto[k0 * 6 + q * 4]);
    wt_[q * 4 + 0] = b.x; wt_[q * 4 + 1] = b.y; wt_[q * 4 + 2] = b.z; wt_[q * 4 + 3] = b.w;
  }
  ushort4 xv4 = *reinterpret_cast<const ushort4*>(&X2[(size_t)r * 256 + k0]);
  float xv[4] = {bf2f(xv4.x), bf2f(xv4.y), bf2f(xv4.z), bf2f(xv4.w)};
  float p[12] = {0.f, 0.f, 0.f, 0.f, 0.f, 0.f, 0.f, 0.f, 0.f, 0.f, 0.f, 0.f};
#pragma unroll
  for (int jj = 0; jj < 4; ++jj)
#pragma unroll
    for (int c = 0; c < 6; ++c) {
      p[c]     += xv[jj] * wr_[jj * 6 + c];
      p[6 + c] += xv[jj] * wt_[jj * 6 + c];
    }
#pragma unroll
  for (int off = 32; off > 0; off >>= 1)
#pragma unroll
    for (int c = 0; c < 12; ++c) p[c] += __shfl_down(p[c], off, 64);
  if (lane == 0) {
#pragma unroll
    for (int c = 0; c < 6; ++c) {
      Pp[(size_t)r * 32 + e * 8 + c] = p[c];
      Qp[(size_t)r * 32 + e * 8 + c] = p[6 + c];
    }
  }
}

// ---------------- head stage 2: gather-style over packed Pp ------------------------
// r9: 32 lanes per dst row, each lane owns one (e,c) slot; per edge the half-wave
// reads one contiguous 128B Pp row (was 4 separate quarter-used 64B txns).
// Per-(e,c) add chain stays ascending-j; final combine expression shape identical
// to r8 (v = s.x*t0; v += s.y*t1; ...) -> bit-identical output.
__global__ void k_headfin_all(const int* __restrict__ row_start,
                              const int* __restrict__ csr_src,
                              const float* __restrict__ Pp, const float* __restrict__ Qp,
                              const float* __restrict__ b_relo,
                              const float* __restrict__ sw, float* __restrict__ out) {
  int tid = threadIdx.x;
  int r = blockIdx.x * 8 + (tid >> 5);    // grid = N/8 exact
  int l32 = tid & 31;
  int e = l32 >> 3, c = l32 & 7;
  int j0 = row_start[r], j1 = row_start[r + 1];
  float av = 0.f;
  int j = j0;
  for (; j + 3 < j1; j += 4) {
    int s0 = csr_src[j];
    int s1 = csr_src[j + 1];
    int s2 = csr_src[j + 2];
    int s3 = csr_src[j + 3];
    float v0 = Pp[(size_t)s0 * 32 + l32];
    float v1 = Pp[(size_t)s1 * 32 + l32];
    float v2 = Pp[(size_t)s2 * 32 + l32];
    float v3 = Pp[(size_t)s3 * 32 + l32];
    av += v0; av += v1; av += v2; av += v3;
  }
  for (; j < j1; ++j) av += Pp[(size_t)csr_src[j] * 32 + l32];
  float q = Qp[(size_t)r * 32 + l32];
  float b = (c < 6) ? b_relo[e * 6 + c] : 0.f;
  float t = av + b + q;
  int base = tid & 32;                   // wave-half origin
  float t0 = __shfl(t, base + c, 64);
  float t1 = __shfl(t, base + 8 + c, 64);
  float t2 = __shfl(t, base + 16 + c, 64);
  float t3 = __shfl(t, base + 24 + c, 64);
  if (e == 0 && c < 6) {
    float4 s4 = *reinterpret_cast<const float4*>(&sw[r * 4]);
    float v = s4.x * t0;
    v += s4.y * t1;
    v += s4.z * t2;
    v += s4.w * t3;
    out[r * 6 + c] = v;
  }
}

// ---------------- launch ----------------
extern "C" void kernel_launch(void* const* d_in, const int* in_sizes, int n_in,
                              void* d_out, int out_size, void* d_ws, size_t ws_size,
                              hipStream_t stream) {
  const float* x        = (const float*)d_in[0];
  const int*   edge     = (const int*)d_in[1];
  const int*   batch    = (const int*)d_in[2];
  const float* enc_w1   = (const float*)d_in[4];
  const float* enc_b1   = (const float*)d_in[5];
  const float* enc_w2   = (const float*)d_in[6];
  const float* enc_b2   = (const float*)d_in[7];
  const float* rt_w1    = (const float*)d_in[8];
  const float* rt_b1    = (const float*)d_in[9];
  const float* ln_g     = (const float*)d_in[10];
  const float* ln_b     = (const float*)d_in[11];
  const float* rt_w2    = (const float*)d_in[12];
  const float* rt_b2    = (const float*)d_in[13];
  const float* centers  = (const float*)d_in[14];
  const float* w_rel    = (const float*)d_in[15];
  const float* b_rel    = (const float*)d_in[16];
  const float* w_root   = (const float*)d_in[17];
  const float* w_relo   = (const float*)d_in[18];
  const float* b_relo   = (const float*)d_in[19];
  const float* w_rooto  = (const float*)d_in[20];
  float* out = (float*)d_out;

  char* wsp = (char*)d_ws;
  auto alloc = [&](size_t bytes) -> char* {
    char* p = wsp;
    wsp += (bytes + 255) & ~(size_t)255;
    return p;
  };
  const size_t actF32 = (size_t)M_PAD * 256 * sizeof(float);    // 51.25 MB
  const size_t actB16 = (size_t)M_PAD * 256 * sizeof(bf16_t);   // 25.63 MB
  char*   hx  = alloc(actF32);    // h; doubles as X1/X2 pair after router
  float*  h   = (float*)hx;
  bf16_t* X1p = (bf16_t*)hx;
  char*   tx  = alloc(actF32);    // t; doubles as A1 pair after encoder GEMM
  float*  t   = (float*)tx;
  bf16_t* A1p = (bf16_t*)tx;
  bf16_t* hb  = (bf16_t*)alloc(actB16);
  bf16_t* AGG = (bf16_t*)alloc(actB16);
  bf16_t* WT  = (bf16_t*)alloc((size_t)16 * 65536 * sizeof(bf16_t));
  float* Pp   = (float*)alloc((size_t)N_NODES * 32 * sizeof(float));   // 6.4 MB
  float* Qp   = (float*)alloc((size_t)N_NODES * 32 * sizeof(float));   // 6.4 MB
  float* wrt  = (float*)alloc((size_t)128 * 256 * sizeof(float));      // 131 KB
  float* swp  = (float*)alloc((size_t)N_NODES * 4 * sizeof(float));
  int*   n_cnt = (int*)alloc(NG * sizeof(int));
  int*   e_cnt = (int*)alloc(NG * sizeof(int));
  float* gfbuf = (float*)alloc(NG * 2 * sizeof(float));
  float* lnn   = (float*)alloc(NG * sizeof(float));
  int* deg       = (int*)alloc((size_t)N_NODES * sizeof(int));
  int* row_start = (int*)alloc((size_t)(N_NODES + 1) * sizeof(int));
  int* cursor    = (int*)alloc((size_t)N_NODES * sizeof(int));
  int* excl      = (int*)alloc((size_t)N_NODES * sizeof(int));
  int* bsum      = (int*)alloc(SCAN_BLK * sizeof(int));
  int* boff      = (int*)alloc(SCAN_BLK * sizeof(int));
  int* csr_src   = (int*)alloc((size_t)NUM_EDGES * sizeof(int));

  // graph stats + CSR build + weight prep
  k_zero<<<(N_NODES + 255) / 256, 256, 0, stream>>>(deg, n_cnt, e_cnt);
  k_count<<<(NUM_EDGES + 255) / 256, 256, 0, stream>>>(batch, edge, n_cnt, e_cnt, deg);
  k_graph_stats<<<1, 64, 0, stream>>>(n_cnt, e_cnt, gfbuf, lnn);
  k_scan_a<<<SCAN_BLK, 256, 0, stream>>>(deg, excl, bsum);
  k_scan_b<<<1, 256, 0, stream>>>(bsum, boff, row_start);
  k_scan_c<<<SCAN_BLK, 256, 0, stream>>>(excl, boff, row_start, cursor);
  k_fill<<<(NUM_EDGES + 255) / 256, 256, 0, stream>>>(edge, cursor, csr_src);
  dim3 wgrid(16, 4);
  k_wprep<<<wgrid, 256, 0, stream>>>(w_rel, w_root, WT);
  k_wrt<<<128, 256, 0, stream>>>(rt_w1, wrt);

  // encoder (frozen math; epilogue also writes hb)
  k_enc1<<<(N_NODES + 15) / 16, 256, 0, stream>>>(x, enc_w1, enc_b1, t);
  dim3 egrid(M_PAD / 128, 2);
  k_gemm_enc<<<egrid, 256, 0, stream>>>(t, enc_w2, enc_b2, h, hb, N_NODES);

  // router (vectorized weight loads via wrt; bit-identical arithmetic)
  k_router_np<<<N_NODES / (4 * NPW), 256, 0, stream>>>(
      h, batch, gfbuf, lnn, wrt, rt_w1, rt_b1, ln_g, ln_b, rt_w2, rt_b2, centers, swp);

  // loop-invariant agg_h (after router: X1p will overwrite h)
  k_gather<<<N_NODES / 8, 256, 0, stream>>>(row_start, csr_src, hb, AGG);

  // experts, pair-batched (GEMMs: global_load_lds staged, 64 rows/block, grid.y = slot)
  dim3 ggrid(M_PAD / 64, 2);
  dim3 grid_gather(N_NODES / 8, 2);
  dim3 grid_pq(N_NODES / 4, 2);
  for (int pe = 0; pe < NEXP; pe += 2) {
    k_gemm1_b<<<ggrid, 256, 0, stream>>>(AGG, hb, WT, b_rel, X1p, pe);
    k_gather_b<<<grid_gather, 256, 0, stream>>>(row_start, csr_src, X1p, A1p);
    k_gemm2_b<<<ggrid, 256, 0, stream>>>(A1p, X1p, WT, b_rel, pe);
    k_headPQ_b<<<grid_pq, 256, 0, stream>>>(X1p, w_relo, w_rooto, Pp, Qp, pe);
  }
  k_headfin_all<<<N_NODES / 8, 256, 0, stream>>>(
      row_start, csr_src, Pp, Qp, b_relo, swp, out);
}

// Round 10
// 1079.347 us; speedup vs baseline: 1.1082x; 1.1082x over previous
//
#include <hip/hip_runtime.h>
#include <math.h>

#define N_NODES 50000
#define M_PAD 50048            // 391 * 128
#define NUM_EDGES 800000
#define NG 8
#define HID 256
#define RHD 128
#define NEXP 4
#define OUTD 6
#define NPW 4                  // router nodes per wave (r15 config: 8 regressed, r18)
#define SCAN_BLK 196           // ceil(50000/256)
#define SRS 136                // padded per-node LN row stride (bank-conflict-free groups)

typedef unsigned short bf16_t;
using f32x4  = __attribute__((ext_vector_type(4))) float;
using bf16x8 = __attribute__((ext_vector_type(8))) short;

__device__ __forceinline__ float bf2f(unsigned short u) {
  union { unsigned int i; float f; } v; v.i = ((unsigned int)u) << 16; return v.f;
}
__device__ __forceinline__ unsigned short f2bf(float f) {
  union { float f; unsigned int i; } v; v.f = f;
  unsigned int x = v.i;
  unsigned int r = x + 0x7fffu + ((x >> 16) & 1u);  // RNE
  return (unsigned short)(r >> 16);
}
__device__ __forceinline__ float readlane_f(float v, int lane) {
  return __int_as_float(__builtin_amdgcn_readlane(__float_as_int(v), lane));
}

// async global->LDS, 16B per lane; LDS dest is wave-uniform base + lane*16 (HW rule)
__device__ __forceinline__ void gl_lds16(const bf16_t* g, bf16_t* l) {
  __builtin_amdgcn_global_load_lds(
      (const __attribute__((address_space(1))) unsigned int*)(g),
      (__attribute__((address_space(3))) unsigned int*)(l), 16, 0, 0);
}

// ---------------- zero init ----------------
__global__ void k_zero(int* __restrict__ deg, int* __restrict__ n_cnt,
                       int* __restrict__ e_cnt) {
  int i = blockIdx.x * blockDim.x + threadIdx.x;
  if (i < N_NODES) deg[i] = 0;
  if (i < NG) { n_cnt[i] = 0; e_cnt[i] = 0; }
}

// ---------------- fused node+edge counts ----------------
__global__ void k_count(const int* __restrict__ batch, const int* __restrict__ edge,
                        int* __restrict__ n_cnt, int* __restrict__ e_cnt,
                        int* __restrict__ deg) {
  __shared__ int histn[NG], histe[NG];
  int t = threadIdx.x;
  if (t < NG) { histn[t] = 0; histe[t] = 0; }
  __syncthreads();
  int i = blockIdx.x * blockDim.x + t;
  if (i < N_NODES) atomicAdd(&histn[batch[i]], 1);
  if (i < NUM_EDGES) {
    int s = edge[i];
    int d = edge[NUM_EDGES + i];
    atomicAdd(&histe[batch[s]], 1);
    atomicAdd(&deg[d], 1);
  }
  __syncthreads();
  if (t < NG) {
    if (histn[t]) atomicAdd(&n_cnt[t], histn[t]);
    if (histe[t]) atomicAdd(&e_cnt[t], histe[t]);
  }
}

// numpy-faithful f32 stats (frozen: razor-sensitive)
__device__ __forceinline__ float tree8(const float* v) {
  float s01 = __fadd_rn(v[0], v[1]);
  float s23 = __fadd_rn(v[2], v[3]);
  float s45 = __fadd_rn(v[4], v[5]);
  float s67 = __fadd_rn(v[6], v[7]);
  return __fadd_rn(__fadd_rn(s01, s23), __fadd_rn(s45, s67));
}

__global__ void k_graph_stats(const int* __restrict__ n_cnt, const int* __restrict__ e_cnt,
                              float* __restrict__ gf, float* __restrict__ lnn) {
  if (threadIdx.x != 0 || blockIdx.x != 0) return;
  float logn[NG], loge[NG];
  for (int g = 0; g < NG; ++g) {
    float nf = fmaxf((float)n_cnt[g], 1.0f);
    logn[g] = (float)log((double)nf);
    float ef = fmaxf((float)e_cnt[g], 0.0f);
    loge[g] = (float)log1p((double)ef);
  }
  float m0 = __fdiv_rn(tree8(logn), 8.0f);
  float m1 = __fdiv_rn(tree8(loge), 8.0f);
  float sq0[NG], sq1[NG];
  float mn = 3.0e38f, mx = -3.0e38f;
  for (int g = 0; g < NG; ++g) {
    float d0 = __fsub_rn(logn[g], m0);
    float d1 = __fsub_rn(loge[g], m1);
    sq0[g] = __fmul_rn(d0, d0);
    sq1[g] = __fmul_rn(d1, d1);
    mn = fminf(mn, logn[g]); mx = fmaxf(mx, logn[g]);
  }
  float s0 = __fadd_rn(sqrtf(__fdiv_rn(tree8(sq0), 8.0f)), 1e-6f);
  float s1 = __fadd_rn(sqrtf(__fdiv_rn(tree8(sq1), 8.0f)), 1e-6f);
  float denom = __fadd_rn(__fsub_rn(mx, mn), 1e-6f);
  for (int g = 0; g < NG; ++g) {
    gf[g * 2 + 0] = __fdiv_rn(__fsub_rn(logn[g], m0), s0);
    gf[g * 2 + 1] = __fdiv_rn(__fsub_rn(loge[g], m1), s1);
    lnn[g] = __fdiv_rn(__fsub_rn(logn[g], mn), denom);
  }
}

// ---------------- CSR build: two-level parallel scan ----------------
__global__ void k_scan_a(const int* __restrict__ deg, int* __restrict__ excl,
                         int* __restrict__ bsum) {
  __shared__ int temp[256];
  int b = blockIdx.x, t = threadIdx.x;
  int i = b * 256 + t;
  int v = (i < N_NODES) ? deg[i] : 0;
  temp[t] = v;
  __syncthreads();
  for (int off = 1; off < 256; off <<= 1) {
    int x = (t >= off) ? temp[t - off] : 0;
    __syncthreads();
    temp[t] += x;
    __syncthreads();
  }
  if (i < N_NODES) excl[i] = temp[t] - v;
  if (t == 255) bsum[b] = temp[255];
}

__global__ void k_scan_b(const int* __restrict__ bsum, int* __restrict__ boff,
                         int* __restrict__ row_start) {
  __shared__ int temp[256];
  int t = threadIdx.x;
  int v = (t < SCAN_BLK) ? bsum[t] : 0;
  temp[t] = v;
  __syncthreads();
  for (int off = 1; off < 256; off <<= 1) {
    int x = (t >= off) ? temp[t - off] : 0;
    __syncthreads();
    temp[t] += x;
    __syncthreads();
  }
  if (t < SCAN_BLK) boff[t] = temp[t] - v;
  if (t == SCAN_BLK - 1) row_start[N_NODES] = temp[t];
}

__global__ void k_scan_c(const int* __restrict__ excl, const int* __restrict__ boff,
                         int* __restrict__ row_start, int* __restrict__ cursor) {
  int i = blockIdx.x * 256 + threadIdx.x;
  if (i < N_NODES) {
    int e = excl[i] + boff[blockIdx.x];
    row_start[i] = e;
    cursor[i] = e;
  }
}

__global__ void k_fill(const int* __restrict__ edge, int* __restrict__ cursor,
                       int* __restrict__ csr_src) {
  int i = blockIdx.x * blockDim.x + threadIdx.x;
  if (i < NUM_EDGES) {
    int d = edge[NUM_EDGES + i];
    int p = atomicAdd(&cursor[d], 1);
    csr_src[p] = edge[i];
  }
}

// ---------------- encoder layer 1 (frozen) -----------------------------------------
__global__ void k_enc1(const float* __restrict__ x, const float* __restrict__ w1,
                       const float* __restrict__ b1, float* __restrict__ t) {
  __shared__ float W[6 * 256];
  __shared__ float xs[16][6];
  int tid = threadIdx.x;
  for (int i = tid; i < 6 * 256; i += 256) W[i] = w1[i];
  int base = blockIdx.x * 16;
  if (tid < 96) {
    int n = tid / 6, k = tid % 6;
    int node = base + n;
    xs[n][k] = (node < N_NODES) ? x[node * 16 + 4 + k] : 0.f;
  }
  __syncthreads();
  float b = b1[tid];
  for (int n = 0; n < 16; ++n) {
    int node = base + n;
    if (node >= N_NODES) break;
    float acc = 0.f;
#pragma unroll
    for (int k = 0; k < 6; ++k) acc = __fmaf_rn(xs[n][k], W[k * 256 + tid], acc);
    t[node * 256 + tid] = fmaxf(__fadd_rn(acc, b), 0.f);
  }
}

// ---------------- fp32 SIMT GEMM (frozen math; epilogue also emits bf16 copy) -------
__global__ __launch_bounds__(256, 2) void k_gemm_enc(
    const float* __restrict__ A, const float* __restrict__ W0,
    const float* __restrict__ bias, float* __restrict__ C,
    bf16_t* __restrict__ Cb, int M) {
  __shared__ float As[16][132];
  __shared__ float Ws[16][128];
  const int tid = threadIdx.x;
  const int tx = tid & 15;
  const int ty = tid >> 4;
  const int rowBase = blockIdx.x * 128;
  const int colBase = blockIdx.y * 128;

  float acc[2][2][4][4];
#pragma unroll
  for (int a = 0; a < 2; ++a)
#pragma unroll
    for (int b = 0; b < 2; ++b)
#pragma unroll
      for (int i = 0; i < 4; ++i)
#pragma unroll
        for (int j = 0; j < 4; ++j) acc[a][b][i][j] = 0.f;

  for (int kt = 0; kt < 16; ++kt) {
    const int kb = kt * 16;
#pragma unroll
    for (int l = 0; l < 2; ++l) {
      int idx = tid + l * 256;
      int m = idx >> 2;
      int kq = (idx & 3) * 4;
      int arow = rowBase + m;
      float4 av = make_float4(0.f, 0.f, 0.f, 0.f);
      if (arow < M) av = *reinterpret_cast<const float4*>(&A[arow * 256 + kb + kq]);
      As[kq + 0][m] = av.x; As[kq + 1][m] = av.y;
      As[kq + 2][m] = av.z; As[kq + 3][m] = av.w;
    }
#pragma unroll
    for (int l = 0; l < 2; ++l) {
      int idx = tid + l * 256;
      int k = idx >> 5;
      int nq = (idx & 31) * 4;
      float4 wv = *reinterpret_cast<const float4*>(&W0[(kb + k) * 256 + colBase + nq]);
      *reinterpret_cast<float4*>(&Ws[k][nq]) = wv;
    }
    __syncthreads();
#pragma unroll
    for (int k = 0; k < 16; ++k) {
      float4 a0 = *reinterpret_cast<const float4*>(&As[k][ty * 4]);
      float4 a1 = *reinterpret_cast<const float4*>(&As[k][64 + ty * 4]);
      float4 w0 = *reinterpret_cast<const float4*>(&Ws[k][tx * 4]);
      float4 w1 = *reinterpret_cast<const float4*>(&Ws[k][64 + tx * 4]);
      float ar[2][4] = {{a0.x, a0.y, a0.z, a0.w}, {a1.x, a1.y, a1.z, a1.w}};
      float wr[2][4] = {{w0.x, w0.y, w0.z, w0.w}, {w1.x, w1.y, w1.z, w1.w}};
#pragma unroll
      for (int ri = 0; ri < 2; ++ri)
#pragma unroll
        for (int i = 0; i < 4; ++i)
#pragma unroll
          for (int ci = 0; ci < 2; ++ci)
#pragma unroll
            for (int j = 0; j < 4; ++j)
              acc[ri][ci][i][j] = __fmaf_rn(ar[ri][i], wr[ci][j], acc[ri][ci][i][j]);
    }
    __syncthreads();
  }
  float4 bv0 = *reinterpret_cast<const float4*>(&bias[colBase + tx * 4]);
  float4 bv1 = *reinterpret_cast<const float4*>(&bias[colBase + 64 + tx * 4]);
  float bb[2][4] = {{bv0.x, bv0.y, bv0.z, bv0.w}, {bv1.x, bv1.y, bv1.z, bv1.w}};
#pragma unroll
  for (int ri = 0; ri < 2; ++ri) {
#pragma unroll
    for (int i = 0; i < 4; ++i) {
      int row = rowBase + ri * 64 + ty * 4 + i;
      if (row < M) {
#pragma unroll
        for (int ci = 0; ci < 2; ++ci) {
          float o[4];
#pragma unroll
          for (int j = 0; j < 4; ++j)
            o[j] = __fadd_rn(acc[ri][ci][i][j], bb[ci][j]);
          *reinterpret_cast<float4*>(&C[row * 256 + colBase + ci * 64 + tx * 4]) =
              make_float4(o[0], o[1], o[2], o[3]);
          ushort4 ob = make_ushort4(f2bf(o[0]), f2bf(o[1]), f2bf(o[2]), f2bf(o[3]));
          *reinterpret_cast<ushort4*>(&Cb[(size_t)row * 256 + colBase + ci * 64 + tx * 4]) = ob;
        }
      }
    }
  }
}

// ---------------- weight prep: transpose f32 [k][n] -> bf16 [n][k] ------------------
__global__ void k_wprep(const float* __restrict__ w_rel, const float* __restrict__ w_root,
                        bf16_t* __restrict__ WT) {
  __shared__ bf16_t tile[64][258];
  int m = blockIdx.x;
  int k0 = blockIdx.y * 64;
  const float* src = (m < 8) ? (w_rel + (size_t)m * 65536)
                             : (w_root + (size_t)(m - 8) * 65536);
  bf16_t* dst = WT + (size_t)m * 65536;
  int tid = threadIdx.x;
  for (int r = 0; r < 64; ++r)
    tile[r][tid] = f2bf(src[(k0 + r) * 256 + tid]);
  __syncthreads();
  for (int c = 0; c < 64; c += 8) {
    ushort4 lo, hi;
    lo.x = tile[c + 0][tid]; lo.y = tile[c + 1][tid];
    lo.z = tile[c + 2][tid]; lo.w = tile[c + 3][tid];
    hi.x = tile[c + 4][tid]; hi.y = tile[c + 5][tid];
    hi.z = tile[c + 6][tid]; hi.w = tile[c + 7][tid];
    *reinterpret_cast<ushort4*>(&dst[tid * 256 + k0 + c]) = lo;
    *reinterpret_cast<ushort4*>(&dst[tid * 256 + k0 + c + 4]) = hi;
  }
}

// ---------------- MFMA bf16 GEMM core: global_load_lds staging, XOR swizzle ---------
// r8: staging via __builtin_amdgcn_global_load_lds width=16 (no VGPR round-trip, no
// ds_write). LDS LINEAR [row][64] (40 KB -> 4 blocks/CU). Bank conflicts on the
// ds_read_b128 fragment reads fixed by both-sides XOR swizzle (guide §5 #21):
// source 16B-slot ^= (row&7) at stage time, read applies the same XOR.
// Same values, same MFMA order -> BIT-IDENTICAL output. In-place gemm2 safety:
// staging loads drained (vmcnt(0)) by the loop's final __syncthreads() before
// epilogue writes; blocks are row-exclusive (64 rows x all 256 cols).
__device__ __forceinline__ void gemm_core64(
    const bf16_t* __restrict__ A, const bf16_t* __restrict__ W0t,
    const bf16_t* __restrict__ B, const bf16_t* __restrict__ W1t,
    const float* __restrict__ bias, bf16_t* __restrict__ C, int rowBase) {
  __shared__ bf16_t As[64 * 64];    // 8 KB linear
  __shared__ bf16_t Bs[256 * 64];   // 32 KB linear
  const int tid = threadIdx.x;
  const int lane = tid & 63;
  const int wave = tid >> 6;
  const int lm = lane & 15;
  const int quad = lane >> 4;
  const int wn = wave * 64;        // col strip: 4 waves cover 256 cols
  const int lrow = lane >> 3;      // row within an 8-row / 1KB segment
  const int lslot = lane & 7;      // 16B slot within 128B row

  f32x4 acc[4][4];
#pragma unroll
  for (int i = 0; i < 4; ++i)
#pragma unroll
    for (int j = 0; j < 4; ++j) acc[i][j] = (f32x4){0.f, 0.f, 0.f, 0.f};

#pragma unroll
  for (int phase = 0; phase < 2; ++phase) {
    const bf16_t* __restrict__ Ain = phase ? B : A;
    const bf16_t* __restrict__ Wt  = phase ? W1t : W0t;
    for (int kc = 0; kc < 4; ++kc) {          // K-chunks of 64
      const int kb = kc * 64;
#pragma unroll
      for (int l = 0; l < 2; ++l) {
        int s = wave * 2 + l;
        int row = s * 8 + lrow;
        int srcc = kb + ((lslot ^ (row & 7)) << 3);
        gl_lds16(&Ain[(size_t)(rowBase + row) * 256 + srcc], &As[s * 512]);
      }
#pragma unroll
      for (int l = 0; l < 8; ++l) {
        int s = wave * 8 + l;
        int row = s * 8 + lrow;
        int srcc = kb + ((lslot ^ (row & 7)) << 3);
        gl_lds16(&Wt[(size_t)row * 256 + srcc], &Bs[s * 512]);
      }
      __syncthreads();   // drains vmcnt(0): staged data visible
#pragma unroll
      for (int k2 = 0; k2 < 2; ++k2) {        // two K=32 sub-steps
        const int c0 = k2 * 32 + quad * 8;
        bf16x8 af[4], bfr[4];
#pragma unroll
        for (int i = 0; i < 4; ++i) {
          int ar = i * 16 + lm;
          af[i] = *reinterpret_cast<const bf16x8*>(&As[ar * 64 + (c0 ^ ((ar & 7) << 3))]);
        }
#pragma unroll
        for (int j = 0; j < 4; ++j) {
          int br = wn + j * 16 + lm;
          bfr[j] = *reinterpret_cast<const bf16x8*>(&Bs[br * 64 + (c0 ^ ((br & 7) << 3))]);
        }
#pragma unroll
        for (int i = 0; i < 4; ++i)
#pragma unroll
          for (int j = 0; j < 4; ++j)
            acc[i][j] = __builtin_amdgcn_mfma_f32_16x16x32_bf16(af[i], bfr[j], acc[i][j], 0, 0, 0);
      }
      __syncthreads();   // LDS reuse next chunk; final one guards in-place epilogue
    }
  }
  float bj[4];
#pragma unroll
  for (int j = 0; j < 4; ++j) bj[j] = bias[wn + j * 16 + lm];
#pragma unroll
  for (int i = 0; i < 4; ++i) {
#pragma unroll
    for (int j = 0; j < 4; ++j) {
      int col = wn + j * 16 + lm;
#pragma unroll
      for (int r = 0; r < 4; ++r) {
        int row = rowBase + i * 16 + quad * 4 + r;
        C[(size_t)row * 256 + col] = f2bf(fmaxf(acc[i][j][r] + bj[j], 0.f));
      }
    }
  }
}

// pair-batched GEMM1: X1[slot] = relu(AGG@wr0_e + hb@wo0_e + br0_e), e = pe + slot
__global__ __launch_bounds__(256, 4) void k_gemm1_b(
    const bf16_t* __restrict__ AGG, const bf16_t* __restrict__ hb,
    const bf16_t* __restrict__ WT, const float* __restrict__ b_rel,
    bf16_t* __restrict__ X1p, int pe) {
  int slot = blockIdx.y, e = pe + slot;
  gemm_core64(AGG, WT + (size_t)(e * 2) * 65536,
              hb, WT + (size_t)(8 + e * 2) * 65536,
              b_rel + (size_t)(e * 2) * 256,
              X1p + (size_t)slot * M_PAD * 256, blockIdx.x * 64);
}

// pair-batched GEMM2 (in-place; row-exclusive blocks + pre-write barrier make it safe)
__global__ __launch_bounds__(256, 4) void k_gemm2_b(
    const bf16_t* __restrict__ A1p, bf16_t* __restrict__ X1p,
    const bf16_t* __restrict__ WT, const float* __restrict__ b_rel, int pe) {
  int slot = blockIdx.y, e = pe + slot;
  bf16_t* Xs = X1p + (size_t)slot * M_PAD * 256;
  gemm_core64(A1p + (size_t)slot * M_PAD * 256, WT + (size_t)(e * 2 + 1) * 65536,
              Xs, WT + (size_t)(8 + e * 2 + 1) * 65536,
              b_rel + (size_t)(e * 2 + 1) * 256, Xs, blockIdx.x * 64);
}

// ---------------- CSR gather, bf16 in/out (f32 accumulate, unroll-4) ----------------
// At its L3-path floor (~106us, invariant to ILP/TLP changes r1..r8) — frozen.
__device__ __forceinline__ void gather_core(
    const int* __restrict__ row_start, const int* __restrict__ csr_src,
    const bf16_t* __restrict__ X, bf16_t* __restrict__ Cout) {
  int tid = threadIdx.x;
  int r = blockIdx.x * 8 + (tid >> 5);
  int f = (tid & 31) * 8;
  int j0 = row_start[r], j1 = row_start[r + 1];
  float a[8] = {0.f, 0.f, 0.f, 0.f, 0.f, 0.f, 0.f, 0.f};
  int j = j0;
  for (; j + 3 < j1; j += 4) {
    int s0 = csr_src[j];
    int s1 = csr_src[j + 1];
    int s2 = csr_src[j + 2];
    int s3 = csr_src[j + 3];
    bf16x8 v0 = *reinterpret_cast<const bf16x8*>(&X[(size_t)s0 * 256 + f]);
    bf16x8 v1 = *reinterpret_cast<const bf16x8*>(&X[(size_t)s1 * 256 + f]);
    bf16x8 v2 = *reinterpret_cast<const bf16x8*>(&X[(size_t)s2 * 256 + f]);
    bf16x8 v3 = *reinterpret_cast<const bf16x8*>(&X[(size_t)s3 * 256 + f]);
#pragma unroll
    for (int t = 0; t < 8; ++t) a[t] += bf2f((unsigned short)v0[t]);
#pragma unroll
    for (int t = 0; t < 8; ++t) a[t] += bf2f((unsigned short)v1[t]);
#pragma unroll
    for (int t = 0; t < 8; ++t) a[t] += bf2f((unsigned short)v2[t]);
#pragma unroll
    for (int t = 0; t < 8; ++t) a[t] += bf2f((unsigned short)v3[t]);
  }
  for (; j < j1; ++j) {
    int s = csr_src[j];
    bf16x8 v = *reinterpret_cast<const bf16x8*>(&X[(size_t)s * 256 + f]);
#pragma unroll
    for (int t = 0; t < 8; ++t) a[t] += bf2f((unsigned short)v[t]);
  }
  ushort4 lo = make_ushort4(f2bf(a[0]), f2bf(a[1]), f2bf(a[2]), f2bf(a[3]));
  ushort4 hi = make_ushort4(f2bf(a[4]), f2bf(a[5]), f2bf(a[6]), f2bf(a[7]));
  *reinterpret_cast<ushort4*>(&Cout[(size_t)r * 256 + f]) = lo;
  *reinterpret_cast<ushort4*>(&Cout[(size_t)r * 256 + f + 4]) = hi;
}

__global__ void k_gather(const int* __restrict__ row_start, const int* __restrict__ csr_src,
                         const bf16_t* __restrict__ X, bf16_t* __restrict__ Cout) {
  gather_core(row_start, csr_src, X, Cout);
}

__global__ void k_gather_b(const int* __restrict__ row_start, const int* __restrict__ csr_src,
                           const bf16_t* __restrict__ X1p, bf16_t* __restrict__ A1p) {
  size_t off = (size_t)blockIdx.y * M_PAD * 256;
  gather_core(row_start, csr_src, X1p + off, A1p + off);
}

// ---------------- numpy-faithful f32 router (r8 form restored) ----------------------
// r10: REVERT of r9's WRT change. rtw1[k*RHD+l] loads are coalesced (l = lane index,
// consecutive lanes read consecutive floats); the r9 transposed-float4 access had 1KB
// lane stride and regressed 95 -> 220us. Per-(node,col) arithmetic BIT-IDENTICAL:
// ascending k chain, gf-then-bias, pairwise-8 LN chains + shfl tree8, f64 exp.
__global__ __launch_bounds__(256) void k_router_np(
    const float* __restrict__ h, const int* __restrict__ batch,
    const float* __restrict__ gf, const float* __restrict__ lnn,
    const float* __restrict__ rtw1, const float* __restrict__ rtb1,
    const float* __restrict__ lng, const float* __restrict__ lnb,
    const float* __restrict__ rtw2, const float* __restrict__ rtb2,
    const float* __restrict__ centers, float* __restrict__ sw) {
  __shared__ float smem[4][1104];
  const int tid = threadIdx.x;
  const int w = tid >> 6;
  const int l = tid & 63;
  const int nbase = blockIdx.x * (4 * NPW) + w * NPW;   // grid = 3125, exact
  float* sm = smem[w];

  // stage h transposed: hT[k][nn], conflict-free b128 writes (16B lane stride)
#pragma unroll
  for (int j = 0; j < 4; ++j) {
    f32x4 v;
#pragma unroll
    for (int nn = 0; nn < NPW; ++nn)
      v[nn] = h[(size_t)(nbase + nn) * 256 + j * 64 + l];
    *reinterpret_cast<f32x4*>(&sm[(j * 64 + l) * 4]) = v;
  }
  __syncthreads();

  float acc0[NPW], acc1[NPW];
#pragma unroll
  for (int nn = 0; nn < NPW; ++nn) { acc0[nn] = 0.f; acc1[nn] = 0.f; }
#pragma unroll
  for (int j = 0; j < 4; ++j) {
#pragma unroll 16
    for (int k2 = 0; k2 < 64; ++k2) {
      int k = j * 64 + k2;
      float w0 = rtw1[k * RHD + l];
      float w1 = rtw1[k * RHD + l + 64];
      f32x4 hv = *reinterpret_cast<const f32x4*>(&sm[k * 4]);  // uniform-addr broadcast
#pragma unroll
      for (int nn = 0; nn < NPW; ++nn) {
        acc0[nn] = __fmaf_rn(hv[nn], w0, acc0[nn]);
        acc1[nn] = __fmaf_rn(hv[nn], w1, acc1[nn]);
      }
    }
  }

  float g0a = rtw1[256 * RHD + l],      g1a = rtw1[257 * RHD + l];
  float g0b = rtw1[256 * RHD + l + 64], g1b = rtw1[257 * RHD + l + 64];
  float b0 = rtb1[l], b1v = rtb1[l + 64];
  float lga = lng[l], lgb = lng[l + 64];
  float lba = lnb[l], lbb = lnb[l + 64];

  float r0[NPW], r1[NPW];
#pragma unroll
  for (int nn = 0; nn < NPW; ++nn) {
    int node = nbase + nn;
    int g = batch[node];
    float gf0 = gf[g * 2 + 0], gf1 = gf[g * 2 + 1];
    float t0 = acc0[nn], t1 = acc1[nn];
    t0 = __fmaf_rn(gf0, g0a, t0);
    t0 = __fmaf_rn(gf1, g1a, t0);
    t1 = __fmaf_rn(gf0, g0b, t1);
    t1 = __fmaf_rn(gf1, g1b, t1);
    r0[nn] = __fadd_rn(t0, b0);
    r1[nn] = __fadd_rn(t1, b1v);
    sm[nn * SRS + l] = r0[nn];
    sm[nn * SRS + 64 + l] = r1[nn];
  }
  __syncthreads();

  // mean reduction: 32 lanes, 8 per node (same 16-term ascending chain per sub-lane)
  float aj = 0.f;
  if (l < 32) {
    const float* Sp = &sm[(l >> 3) * SRS];
    int rj = l & 7;
    aj = Sp[rj];
    for (int i = 8; i < 128; i += 8) aj = __fadd_rn(aj, Sp[i + rj]);
  }
  float mu[NPW];
#pragma unroll
  for (int nn = 0; nn < NPW; ++nn) {
    float a0 = __shfl(aj, nn * 8 + 0, 64), a1 = __shfl(aj, nn * 8 + 1, 64);
    float a2 = __shfl(aj, nn * 8 + 2, 64), a3 = __shfl(aj, nn * 8 + 3, 64);
    float a4 = __shfl(aj, nn * 8 + 4, 64), a5 = __shfl(aj, nn * 8 + 5, 64);
    float a6 = __shfl(aj, nn * 8 + 6, 64), a7 = __shfl(aj, nn * 8 + 7, 64);
    float s01 = __fadd_rn(a0, a1), s23 = __fadd_rn(a2, a3);
    float s45 = __fadd_rn(a4, a5), s67 = __fadd_rn(a6, a7);
    float t = __fadd_rn(__fadd_rn(s01, s23), __fadd_rn(s45, s67));
    mu[nn] = __fdiv_rn(t, 128.0f);
  }

  float d0[NPW], d1[NPW];
#pragma unroll
  for (int nn = 0; nn < NPW; ++nn) {
    d0[nn] = __fsub_rn(r0[nn], mu[nn]);
    d1[nn] = __fsub_rn(r1[nn], mu[nn]);
    sm[nn * SRS + l] = __fmul_rn(d0[nn], d0[nn]);
    sm[nn * SRS + 64 + l] = __fmul_rn(d1[nn], d1[nn]);
  }
  __syncthreads();

  // variance reduction (identical chain structure)
  float qj = 0.f;
  if (l < 32) {
    const float* Sp = &sm[(l >> 3) * SRS];
    int rj = l & 7;
    qj = Sp[rj];
    for (int i = 8; i < 128; i += 8) qj = __fadd_rn(qj, Sp[i + rj]);
  }
#pragma unroll
  for (int nn = 0; nn < NPW; ++nn) {
    float a0 = __shfl(qj, nn * 8 + 0, 64), a1 = __shfl(qj, nn * 8 + 1, 64);
    float a2 = __shfl(qj, nn * 8 + 2, 64), a3 = __shfl(qj, nn * 8 + 3, 64);
    float a4 = __shfl(qj, nn * 8 + 4, 64), a5 = __shfl(qj, nn * 8 + 5, 64);
    float a6 = __shfl(qj, nn * 8 + 6, 64), a7 = __shfl(qj, nn * 8 + 7, 64);
    float s01 = __fadd_rn(a0, a1), s23 = __fadd_rn(a2, a3);
    float s45 = __fadd_rn(a4, a5), s67 = __fadd_rn(a6, a7);
    float t = __fadd_rn(__fadd_rn(s01, s23), __fadd_rn(s45, s67));
    float var = __fdiv_rn(t, 128.0f);
    float inv = __fdiv_rn(1.0f, sqrtf(__fadd_rn(var, 1e-5f)));
    float y0 = __fadd_rn(__fmul_rn(__fmul_rn(d0[nn], inv), lga), lba);
    float y1 = __fadd_rn(__fmul_rn(__fmul_rn(d1[nn], inv), lgb), lbb);
    sm[544 + nn * SRS + l] = fmaxf(y0, 0.f);
    sm[544 + nn * SRS + 64 + l] = fmaxf(y1, 0.f);
  }
  __syncthreads();

  // head: 16 lanes = 4 nodes x 4 cols, same serial 128-FMA ascending chain per col
  if (l < 16) {
    int nn = l >> 2, c = l & 3;
    int node = nbase + nn;
    const float* Ap = &sm[544 + nn * SRS];
    float acc = 0.f;
    for (int k = 0; k < 128; ++k) acc = __fmaf_rn(Ap[k], rtw2[k * 4 + c], acc);
    float lrn = __fadd_rn(acc, rtb2[c]);
    float nl = lnn[batch[node]];
    float dd = __fsub_rn(nl, centers[c]);
    float pr = -__fmul_rn(dd, dd);
    sm[1088 + nn * 4 + c] = __fadd_rn(__fmul_rn(0.65f, lrn), __fmul_rn(0.35f, pr));
  }
  __syncthreads();

  // softmax + top2: 4 lanes = 4 nodes (identical code to l==0 path)
  if (l < NPW) {
    int nn = l;
    int node = nbase + nn;
    float lg[4] = {sm[1088 + nn * 4 + 0], sm[1088 + nn * 4 + 1],
                   sm[1088 + nn * 4 + 2], sm[1088 + nn * 4 + 3]};
    float mx = fmaxf(fmaxf(lg[0], lg[1]), fmaxf(lg[2], lg[3]));
    float e[4];
#pragma unroll
    for (int c = 0; c < 4; ++c)
      e[c] = (float)exp((double)__fsub_rn(lg[c], mx));
    float S = __fadd_rn(__fadd_rn(__fadd_rn(e[0], e[1]), e[2]), e[3]);
    float p[4];
#pragma unroll
    for (int c = 0; c < 4; ++c) p[c] = __fdiv_rn(e[c], S);
    int i1 = 0;
#pragma unroll
    for (int c = 1; c < 4; ++c) if (p[c] > p[i1]) i1 = c;
    int i2 = -1;
#pragma unroll
    for (int c = 0; c < 4; ++c) {
      if (c == i1) continue;
      if (i2 < 0 || p[c] > p[i2]) i2 = c;
    }
    float den = __fadd_rn(__fadd_rn(p[i1], p[i2]), 1e-8f);
    float swv[4] = {0.f, 0.f, 0.f, 0.f};
    swv[i1] = __fdiv_rn(p[i1], den);
    swv[i2] = __fdiv_rn(p[i2], den);
    *reinterpret_cast<float4*>(&sw[node * 4]) =
        make_float4(swv[0], swv[1], swv[2], swv[3]);
  }
}

// ---------------- head stage 1 (pair-batched): packed Pp/Qp[n][e*8+c] ---------------
// P (gatherable) and Q (root) stored e-major packed 32-float rows so the headfin
// gather reads one contiguous 128B row per edge. Same computed values as r8.
__global__ void k_headPQ_b(const bf16_t* __restrict__ X2p,
                           const float* __restrict__ w_relo, const float* __restrict__ w_rooto,
                           float* __restrict__ Pp, float* __restrict__ Qp, int pe) {
  int slot = blockIdx.y, e = pe + slot;
  const bf16_t* X2 = X2p + (size_t)slot * M_PAD * 256;
  const float* wro = w_relo + (size_t)e * 256 * OUTD;
  const float* wto = w_rooto + (size_t)e * 256 * OUTD;
  int tid = threadIdx.x;
  int r = blockIdx.x * 4 + (tid >> 6);    // grid.x = N/4 exact
  int lane = tid & 63;
  int k0 = lane * 4;
  float wr_[24], wt_[24];
#pragma unroll
  for (int q = 0; q < 6; ++q) {
    float4 a = *reinterpret_cast<const float4*>(&wro[k0 * 6 + q * 4]);
    wr_[q * 4 + 0] = a.x; wr_[q * 4 + 1] = a.y; wr_[q * 4 + 2] = a.z; wr_[q * 4 + 3] = a.w;
    float4 b = *reinterpret_cast<const float4*>(&wto[k0 * 6 + q * 4]);
    wt_[q * 4 + 0] = b.x; wt_[q * 4 + 1] = b.y; wt_[q * 4 + 2] = b.z; wt_[q * 4 + 3] = b.w;
  }
  ushort4 xv4 = *reinterpret_cast<const ushort4*>(&X2[(size_t)r * 256 + k0]);
  float xv[4] = {bf2f(xv4.x), bf2f(xv4.y), bf2f(xv4.z), bf2f(xv4.w)};
  float p[12] = {0.f, 0.f, 0.f, 0.f, 0.f, 0.f, 0.f, 0.f, 0.f, 0.f, 0.f, 0.f};
#pragma unroll
  for (int jj = 0; jj < 4; ++jj)
#pragma unroll
    for (int c = 0; c < 6; ++c) {
      p[c]     += xv[jj] * wr_[jj * 6 + c];
      p[6 + c] += xv[jj] * wt_[jj * 6 + c];
    }
#pragma unroll
  for (int off = 32; off > 0; off >>= 1)
#pragma unroll
    for (int c = 0; c < 12; ++c) p[c] += __shfl_down(p[c], off, 64);
  if (lane == 0) {
#pragma unroll
    for (int c = 0; c < 6; ++c) {
      Pp[(size_t)r * 32 + e * 8 + c] = p[c];
      Qp[(size_t)r * 32 + e * 8 + c] = p[6 + c];
    }
  }
}

// ---------------- head stage 2: gather-style over packed Pp ------------------------
// 32 lanes per dst row, each lane owns one (e,c) slot; per edge the half-wave reads
// one contiguous 128B Pp row. Per-(e,c) add chain ascending-j; final combine
// expression shape identical to r8 -> bit-identical output.
__global__ void k_headfin_all(const int* __restrict__ row_start,
                              const int* __restrict__ csr_src,
                              const float* __restrict__ Pp, const float* __restrict__ Qp,
                              const float* __restrict__ b_relo,
                              const float* __restrict__ sw, float* __restrict__ out) {
  int tid = threadIdx.x;
  int r = blockIdx.x * 8 + (tid >> 5);    // grid = N/8 exact
  int l32 = tid & 31;
  int e = l32 >> 3, c = l32 & 7;
  int j0 = row_start[r], j1 = row_start[r + 1];
  float av = 0.f;
  int j = j0;
  for (; j + 3 < j1; j += 4) {
    int s0 = csr_src[j];
    int s1 = csr_src[j + 1];
    int s2 = csr_src[j + 2];
    int s3 = csr_src[j + 3];
    float v0 = Pp[(size_t)s0 * 32 + l32];
    float v1 = Pp[(size_t)s1 * 32 + l32];
    float v2 = Pp[(size_t)s2 * 32 + l32];
    float v3 = Pp[(size_t)s3 * 32 + l32];
    av += v0; av += v1; av += v2; av += v3;
  }
  for (; j < j1; ++j) av += Pp[(size_t)csr_src[j] * 32 + l32];
  float q = Qp[(size_t)r * 32 + l32];
  float b = (c < 6) ? b_relo[e * 6 + c] : 0.f;
  float t = av + b + q;
  int base = tid & 32;                   // wave-half origin
  float t0 = __shfl(t, base + c, 64);
  float t1 = __shfl(t, base + 8 + c, 64);
  float t2 = __shfl(t, base + 16 + c, 64);
  float t3 = __shfl(t, base + 24 + c, 64);
  if (e == 0 && c < 6) {
    float4 s4 = *reinterpret_cast<const float4*>(&sw[r * 4]);
    float v = s4.x * t0;
    v += s4.y * t1;
    v += s4.z * t2;
    v += s4.w * t3;
    out[r * 6 + c] = v;
  }
}

// ---------------- launch ----------------
extern "C" void kernel_launch(void* const* d_in, const int* in_sizes, int n_in,
                              void* d_out, int out_size, void* d_ws, size_t ws_size,
                              hipStream_t stream) {
  const float* x        = (const float*)d_in[0];
  const int*   edge     = (const int*)d_in[1];
  const int*   batch    = (const int*)d_in[2];
  const float* enc_w1   = (const float*)d_in[4];
  const float* enc_b1   = (const float*)d_in[5];
  const float* enc_w2   = (const float*)d_in[6];
  const float* enc_b2   = (const float*)d_in[7];
  const float* rt_w1    = (const float*)d_in[8];
  const float* rt_b1    = (const float*)d_in[9];
  const float* ln_g     = (const float*)d_in[10];
  const float* ln_b     = (const float*)d_in[11];
  const float* rt_w2    = (const float*)d_in[12];
  const float* rt_b2    = (const float*)d_in[13];
  const float* centers  = (const float*)d_in[14];
  const float* w_rel    = (const float*)d_in[15];
  const float* b_rel    = (const float*)d_in[16];
  const float* w_root   = (const float*)d_in[17];
  const float* w_relo   = (const float*)d_in[18];
  const float* b_relo   = (const float*)d_in[19];
  const float* w_rooto  = (const float*)d_in[20];
  float* out = (float*)d_out;

  char* wsp = (char*)d_ws;
  auto alloc = [&](size_t bytes) -> char* {
    char* p = wsp;
    wsp += (bytes + 255) & ~(size_t)255;
    return p;
  };
  const size_t actF32 = (size_t)M_PAD * 256 * sizeof(float);    // 51.25 MB
  const size_t actB16 = (size_t)M_PAD * 256 * sizeof(bf16_t);   // 25.63 MB
  char*   hx  = alloc(actF32);    // h; doubles as X1/X2 pair after router
  float*  h   = (float*)hx;
  bf16_t* X1p = (bf16_t*)hx;
  char*   tx  = alloc(actF32);    // t; doubles as A1 pair after encoder GEMM
  float*  t   = (float*)tx;
  bf16_t* A1p = (bf16_t*)tx;
  bf16_t* hb  = (bf16_t*)alloc(actB16);
  bf16_t* AGG = (bf16_t*)alloc(actB16);
  bf16_t* WT  = (bf16_t*)alloc((size_t)16 * 65536 * sizeof(bf16_t));
  float* Pp   = (float*)alloc((size_t)N_NODES * 32 * sizeof(float));   // 6.4 MB
  float* Qp   = (float*)alloc((size_t)N_NODES * 32 * sizeof(float));   // 6.4 MB
  float* swp  = (float*)alloc((size_t)N_NODES * 4 * sizeof(float));
  int*   n_cnt = (int*)alloc(NG * sizeof(int));
  int*   e_cnt = (int*)alloc(NG * sizeof(int));
  float* gfbuf = (float*)alloc(NG * 2 * sizeof(float));
  float* lnn   = (float*)alloc(NG * sizeof(float));
  int* deg       = (int*)alloc((size_t)N_NODES * sizeof(int));
  int* row_start = (int*)alloc((size_t)(N_NODES + 1) * sizeof(int));
  int* cursor    = (int*)alloc((size_t)N_NODES * sizeof(int));
  int* excl      = (int*)alloc((size_t)N_NODES * sizeof(int));
  int* bsum      = (int*)alloc(SCAN_BLK * sizeof(int));
  int* boff      = (int*)alloc(SCAN_BLK * sizeof(int));
  int* csr_src   = (int*)alloc((size_t)NUM_EDGES * sizeof(int));

  // graph stats + CSR build + weight prep
  k_zero<<<(N_NODES + 255) / 256, 256, 0, stream>>>(deg, n_cnt, e_cnt);
  k_count<<<(NUM_EDGES + 255) / 256, 256, 0, stream>>>(batch, edge, n_cnt, e_cnt, deg);
  k_graph_stats<<<1, 64, 0, stream>>>(n_cnt, e_cnt, gfbuf, lnn);
  k_scan_a<<<SCAN_BLK, 256, 0, stream>>>(deg, excl, bsum);
  k_scan_b<<<1, 256, 0, stream>>>(bsum, boff, row_start);
  k_scan_c<<<SCAN_BLK, 256, 0, stream>>>(excl, boff, row_start, cursor);
  k_fill<<<(NUM_EDGES + 255) / 256, 256, 0, stream>>>(edge, cursor, csr_src);
  dim3 wgrid(16, 4);
  k_wprep<<<wgrid, 256, 0, stream>>>(w_rel, w_root, WT);

  // encoder (frozen math; epilogue also writes hb)
  k_enc1<<<(N_NODES + 15) / 16, 256, 0, stream>>>(x, enc_w1, enc_b1, t);
  dim3 egrid(M_PAD / 128, 2);
  k_gemm_enc<<<egrid, 256, 0, stream>>>(t, enc_w2, enc_b2, h, hb, N_NODES);

  // router (r8 form: coalesced scalar weight loads; bit-identical arithmetic)
  k_router_np<<<N_NODES / (4 * NPW), 256, 0, stream>>>(
      h, batch, gfbuf, lnn, rt_w1, rt_b1, ln_g, ln_b, rt_w2, rt_b2, centers, swp);

  // loop-invariant agg_h (after router: X1p will overwrite h)
  k_gather<<<N_NODES / 8, 256, 0, stream>>>(row_start, csr_src, hb, AGG);

  // experts, pair-batched (GEMMs: global_load_lds staged, 64 rows/block, grid.y = slot)
  dim3 ggrid(M_PAD / 64, 2);
  dim3 grid_gather(N_NODES / 8, 2);
  dim3 grid_pq(N_NODES / 4, 2);
  for (int pe = 0; pe < NEXP; pe += 2) {
    k_gemm1_b<<<ggrid, 256, 0, stream>>>(AGG, hb, WT, b_rel, X1p, pe);
    k_gather_b<<<grid_gather, 256, 0, stream>>>(row_start, csr_src, X1p, A1p);
    k_gemm2_b<<<ggrid, 256, 0, stream>>>(A1p, X1p, WT, b_rel, pe);
    k_headPQ_b<<<grid_pq, 256, 0, stream>>>(X1p, w_relo, w_rooto, Pp, Qp, pe);
  }
  k_headfin_all<<<N_NODES / 8, 256, 0, stream>>>(
      row_start, csr_src, Pp, Qp, b_relo, swp, out);
}

// Round 11
// 1001.890 us; speedup vs baseline: 1.1939x; 1.0773x over previous
//
#include <hip/hip_runtime.h>
#include <math.h>

#define N_NODES 50000
#define M_PAD 50048            // 391 * 128
#define NUM_EDGES 800000
#define NG 8
#define HID 256
#define RHD 128
#define NEXP 4
#define OUTD 6
#define NPW 4                  // router nodes per wave (r15 config: 8 regressed, r18)
#define SCAN_BLK 196           // ceil(50000/256)
#define SRS 136                // padded per-node LN row stride (bank-conflict-free groups)

typedef unsigned short bf16_t;
using f32x4  = __attribute__((ext_vector_type(4))) float;
using bf16x8 = __attribute__((ext_vector_type(8))) short;

__device__ __forceinline__ float bf2f(unsigned short u) {
  union { unsigned int i; float f; } v; v.i = ((unsigned int)u) << 16; return v.f;
}
__device__ __forceinline__ unsigned short f2bf(float f) {
  union { float f; unsigned int i; } v; v.f = f;
  unsigned int x = v.i;
  unsigned int r = x + 0x7fffu + ((x >> 16) & 1u);  // RNE
  return (unsigned short)(r >> 16);
}
__device__ __forceinline__ float readlane_f(float v, int lane) {
  return __int_as_float(__builtin_amdgcn_readlane(__float_as_int(v), lane));
}

// async global->LDS, 16B per lane; LDS dest is wave-uniform base + lane*16 (HW rule)
__device__ __forceinline__ void gl_lds16(const bf16_t* g, bf16_t* l) {
  __builtin_amdgcn_global_load_lds(
      (const __attribute__((address_space(1))) unsigned int*)(g),
      (__attribute__((address_space(3))) unsigned int*)(l), 16, 0, 0);
}

// ---------------- zero init ----------------
__global__ void k_zero(int* __restrict__ deg, int* __restrict__ n_cnt,
                       int* __restrict__ e_cnt) {
  int i = blockIdx.x * blockDim.x + threadIdx.x;
  if (i < N_NODES) deg[i] = 0;
  if (i < NG) { n_cnt[i] = 0; e_cnt[i] = 0; }
}

// ---------------- fused node+edge counts ----------------
__global__ void k_count(const int* __restrict__ batch, const int* __restrict__ edge,
                        int* __restrict__ n_cnt, int* __restrict__ e_cnt,
                        int* __restrict__ deg) {
  __shared__ int histn[NG], histe[NG];
  int t = threadIdx.x;
  if (t < NG) { histn[t] = 0; histe[t] = 0; }
  __syncthreads();
  int i = blockIdx.x * blockDim.x + t;
  if (i < N_NODES) atomicAdd(&histn[batch[i]], 1);
  if (i < NUM_EDGES) {
    int s = edge[i];
    int d = edge[NUM_EDGES + i];
    atomicAdd(&histe[batch[s]], 1);
    atomicAdd(&deg[d], 1);
  }
  __syncthreads();
  if (t < NG) {
    if (histn[t]) atomicAdd(&n_cnt[t], histn[t]);
    if (histe[t]) atomicAdd(&e_cnt[t], histe[t]);
  }
}

// numpy-faithful f32 stats (frozen: razor-sensitive)
__device__ __forceinline__ float tree8(const float* v) {
  float s01 = __fadd_rn(v[0], v[1]);
  float s23 = __fadd_rn(v[2], v[3]);
  float s45 = __fadd_rn(v[4], v[5]);
  float s67 = __fadd_rn(v[6], v[7]);
  return __fadd_rn(__fadd_rn(s01, s23), __fadd_rn(s45, s67));
}

__global__ void k_graph_stats(const int* __restrict__ n_cnt, const int* __restrict__ e_cnt,
                              float* __restrict__ gf, float* __restrict__ lnn) {
  if (threadIdx.x != 0 || blockIdx.x != 0) return;
  float logn[NG], loge[NG];
  for (int g = 0; g < NG; ++g) {
    float nf = fmaxf((float)n_cnt[g], 1.0f);
    logn[g] = (float)log((double)nf);
    float ef = fmaxf((float)e_cnt[g], 0.0f);
    loge[g] = (float)log1p((double)ef);
  }
  float m0 = __fdiv_rn(tree8(logn), 8.0f);
  float m1 = __fdiv_rn(tree8(loge), 8.0f);
  float sq0[NG], sq1[NG];
  float mn = 3.0e38f, mx = -3.0e38f;
  for (int g = 0; g < NG; ++g) {
    float d0 = __fsub_rn(logn[g], m0);
    float d1 = __fsub_rn(loge[g], m1);
    sq0[g] = __fmul_rn(d0, d0);
    sq1[g] = __fmul_rn(d1, d1);
    mn = fminf(mn, logn[g]); mx = fmaxf(mx, logn[g]);
  }
  float s0 = __fadd_rn(sqrtf(__fdiv_rn(tree8(sq0), 8.0f)), 1e-6f);
  float s1 = __fadd_rn(sqrtf(__fdiv_rn(tree8(sq1), 8.0f)), 1e-6f);
  float denom = __fadd_rn(__fsub_rn(mx, mn), 1e-6f);
  for (int g = 0; g < NG; ++g) {
    gf[g * 2 + 0] = __fdiv_rn(__fsub_rn(logn[g], m0), s0);
    gf[g * 2 + 1] = __fdiv_rn(__fsub_rn(loge[g], m1), s1);
    lnn[g] = __fdiv_rn(__fsub_rn(logn[g], mn), denom);
  }
}

// ---------------- CSR build: two-level parallel scan ----------------
__global__ void k_scan_a(const int* __restrict__ deg, int* __restrict__ excl,
                         int* __restrict__ bsum) {
  __shared__ int temp[256];
  int b = blockIdx.x, t = threadIdx.x;
  int i = b * 256 + t;
  int v = (i < N_NODES) ? deg[i] : 0;
  temp[t] = v;
  __syncthreads();
  for (int off = 1; off < 256; off <<= 1) {
    int x = (t >= off) ? temp[t - off] : 0;
    __syncthreads();
    temp[t] += x;
    __syncthreads();
  }
  if (i < N_NODES) excl[i] = temp[t] - v;
  if (t == 255) bsum[b] = temp[255];
}

__global__ void k_scan_b(const int* __restrict__ bsum, int* __restrict__ boff,
                         int* __restrict__ row_start) {
  __shared__ int temp[256];
  int t = threadIdx.x;
  int v = (t < SCAN_BLK) ? bsum[t] : 0;
  temp[t] = v;
  __syncthreads();
  for (int off = 1; off < 256; off <<= 1) {
    int x = (t >= off) ? temp[t - off] : 0;
    __syncthreads();
    temp[t] += x;
    __syncthreads();
  }
  if (t < SCAN_BLK) boff[t] = temp[t] - v;
  if (t == SCAN_BLK - 1) row_start[N_NODES] = temp[t];
}

__global__ void k_scan_c(const int* __restrict__ excl, const int* __restrict__ boff,
                         int* __restrict__ row_start, int* __restrict__ cursor) {
  int i = blockIdx.x * 256 + threadIdx.x;
  if (i < N_NODES) {
    int e = excl[i] + boff[blockIdx.x];
    row_start[i] = e;
    cursor[i] = e;
  }
}

__global__ void k_fill(const int* __restrict__ edge, int* __restrict__ cursor,
                       int* __restrict__ csr_src) {
  int i = blockIdx.x * blockDim.x + threadIdx.x;
  if (i < NUM_EDGES) {
    int d = edge[NUM_EDGES + i];
    int p = atomicAdd(&cursor[d], 1);
    csr_src[p] = edge[i];
  }
}

// ---------------- encoder layer 1 (frozen) -----------------------------------------
__global__ void k_enc1(const float* __restrict__ x, const float* __restrict__ w1,
                       const float* __restrict__ b1, float* __restrict__ t) {
  __shared__ float W[6 * 256];
  __shared__ float xs[16][6];
  int tid = threadIdx.x;
  for (int i = tid; i < 6 * 256; i += 256) W[i] = w1[i];
  int base = blockIdx.x * 16;
  if (tid < 96) {
    int n = tid / 6, k = tid % 6;
    int node = base + n;
    xs[n][k] = (node < N_NODES) ? x[node * 16 + 4 + k] : 0.f;
  }
  __syncthreads();
  float b = b1[tid];
  for (int n = 0; n < 16; ++n) {
    int node = base + n;
    if (node >= N_NODES) break;
    float acc = 0.f;
#pragma unroll
    for (int k = 0; k < 6; ++k) acc = __fmaf_rn(xs[n][k], W[k * 256 + tid], acc);
    t[node * 256 + tid] = fmaxf(__fadd_rn(acc, b), 0.f);
  }
}

// ---------------- fp32 SIMT GEMM (frozen math; epilogue also emits bf16 copy) -------
__global__ __launch_bounds__(256, 2) void k_gemm_enc(
    const float* __restrict__ A, const float* __restrict__ W0,
    const float* __restrict__ bias, float* __restrict__ C,
    bf16_t* __restrict__ Cb, int M) {
  __shared__ float As[16][132];
  __shared__ float Ws[16][128];
  const int tid = threadIdx.x;
  const int tx = tid & 15;
  const int ty = tid >> 4;
  const int rowBase = blockIdx.x * 128;
  const int colBase = blockIdx.y * 128;

  float acc[2][2][4][4];
#pragma unroll
  for (int a = 0; a < 2; ++a)
#pragma unroll
    for (int b = 0; b < 2; ++b)
#pragma unroll
      for (int i = 0; i < 4; ++i)
#pragma unroll
        for (int j = 0; j < 4; ++j) acc[a][b][i][j] = 0.f;

  for (int kt = 0; kt < 16; ++kt) {
    const int kb = kt * 16;
#pragma unroll
    for (int l = 0; l < 2; ++l) {
      int idx = tid + l * 256;
      int m = idx >> 2;
      int kq = (idx & 3) * 4;
      int arow = rowBase + m;
      float4 av = make_float4(0.f, 0.f, 0.f, 0.f);
      if (arow < M) av = *reinterpret_cast<const float4*>(&A[arow * 256 + kb + kq]);
      As[kq + 0][m] = av.x; As[kq + 1][m] = av.y;
      As[kq + 2][m] = av.z; As[kq + 3][m] = av.w;
    }
#pragma unroll
    for (int l = 0; l < 2; ++l) {
      int idx = tid + l * 256;
      int k = idx >> 5;
      int nq = (idx & 31) * 4;
      float4 wv = *reinterpret_cast<const float4*>(&W0[(kb + k) * 256 + colBase + nq]);
      *reinterpret_cast<float4*>(&Ws[k][nq]) = wv;
    }
    __syncthreads();
#pragma unroll
    for (int k = 0; k < 16; ++k) {
      float4 a0 = *reinterpret_cast<const float4*>(&As[k][ty * 4]);
      float4 a1 = *reinterpret_cast<const float4*>(&As[k][64 + ty * 4]);
      float4 w0 = *reinterpret_cast<const float4*>(&Ws[k][tx * 4]);
      float4 w1 = *reinterpret_cast<const float4*>(&Ws[k][64 + tx * 4]);
      float ar[2][4] = {{a0.x, a0.y, a0.z, a0.w}, {a1.x, a1.y, a1.z, a1.w}};
      float wr[2][4] = {{w0.x, w0.y, w0.z, w0.w}, {w1.x, w1.y, w1.z, w1.w}};
#pragma unroll
      for (int ri = 0; ri < 2; ++ri)
#pragma unroll
        for (int i = 0; i < 4; ++i)
#pragma unroll
          for (int ci = 0; ci < 2; ++ci)
#pragma unroll
            for (int j = 0; j < 4; ++j)
              acc[ri][ci][i][j] = __fmaf_rn(ar[ri][i], wr[ci][j], acc[ri][ci][i][j]);
    }
    __syncthreads();
  }
  float4 bv0 = *reinterpret_cast<const float4*>(&bias[colBase + tx * 4]);
  float4 bv1 = *reinterpret_cast<const float4*>(&bias[colBase + 64 + tx * 4]);
  float bb[2][4] = {{bv0.x, bv0.y, bv0.z, bv0.w}, {bv1.x, bv1.y, bv1.z, bv1.w}};
#pragma unroll
  for (int ri = 0; ri < 2; ++ri) {
#pragma unroll
    for (int i = 0; i < 4; ++i) {
      int row = rowBase + ri * 64 + ty * 4 + i;
      if (row < M) {
#pragma unroll
        for (int ci = 0; ci < 2; ++ci) {
          float o[4];
#pragma unroll
          for (int j = 0; j < 4; ++j)
            o[j] = __fadd_rn(acc[ri][ci][i][j], bb[ci][j]);
          *reinterpret_cast<float4*>(&C[row * 256 + colBase + ci * 64 + tx * 4]) =
              make_float4(o[0], o[1], o[2], o[3]);
          ushort4 ob = make_ushort4(f2bf(o[0]), f2bf(o[1]), f2bf(o[2]), f2bf(o[3]));
          *reinterpret_cast<ushort4*>(&Cb[(size_t)row * 256 + colBase + ci * 64 + tx * 4]) = ob;
        }
      }
    }
  }
}

// ---------------- weight prep: transpose f32 [k][n] -> bf16 [n][k] ------------------
__global__ void k_wprep(const float* __restrict__ w_rel, const float* __restrict__ w_root,
                        bf16_t* __restrict__ WT) {
  __shared__ bf16_t tile[64][258];
  int m = blockIdx.x;
  int k0 = blockIdx.y * 64;
  const float* src = (m < 8) ? (w_rel + (size_t)m * 65536)
                             : (w_root + (size_t)(m - 8) * 65536);
  bf16_t* dst = WT + (size_t)m * 65536;
  int tid = threadIdx.x;
  for (int r = 0; r < 64; ++r)
    tile[r][tid] = f2bf(src[(k0 + r) * 256 + tid]);
  __syncthreads();
  for (int c = 0; c < 64; c += 8) {
    ushort4 lo, hi;
    lo.x = tile[c + 0][tid]; lo.y = tile[c + 1][tid];
    lo.z = tile[c + 2][tid]; lo.w = tile[c + 3][tid];
    hi.x = tile[c + 4][tid]; hi.y = tile[c + 5][tid];
    hi.z = tile[c + 6][tid]; hi.w = tile[c + 7][tid];
    *reinterpret_cast<ushort4*>(&dst[tid * 256 + k0 + c]) = lo;
    *reinterpret_cast<ushort4*>(&dst[tid * 256 + k0 + c + 4]) = hi;
  }
}

// ---------------- MFMA bf16 GEMM core: 128 rows/block, global_load_lds, XOR swizzle -
// r11 (on r8's staging): block tile 64 -> 128 rows (acc[8][4], ~200 VGPR, 2 blocks/CU
// via launch_bounds(256,2)). Rationale: r8's limiter is the vmcnt(0) drain at each of
// 8 K-chunk barriers (~45us of the 69us dispatch); doubling MFMAs per drain (32->64
// per wave) halves the stall fraction, and W re-reads per dispatch halve (391 blocks
// share the same 512KB of weights). r6 showed this kernel is occupancy-insensitive,
// so trading blocks/CU (4->2) for per-barrier work is the right trade.
// Phase order, kc order, k2 order and fragment contents are UNCHANGED per (row,col)
// -> BIT-IDENTICAL output. In-place gemm2 safety: blocks row-exclusive (128 rows x
// all 256 cols); final loop barrier (drains vmcnt0) precedes epilogue writes.
__device__ __forceinline__ void gemm_core128(
    const bf16_t* __restrict__ A, const bf16_t* __restrict__ W0t,
    const bf16_t* __restrict__ B, const bf16_t* __restrict__ W1t,
    const float* __restrict__ bias, bf16_t* __restrict__ C, int rowBase) {
  __shared__ bf16_t As[128 * 64];   // 16 KB linear
  __shared__ bf16_t Bs[256 * 64];   // 32 KB linear
  const int tid = threadIdx.x;
  const int lane = tid & 63;
  const int wave = tid >> 6;
  const int lm = lane & 15;
  const int quad = lane >> 4;
  const int wn = wave * 64;        // col strip: 4 waves cover 256 cols
  const int lrow = lane >> 3;      // row within an 8-row / 1KB segment
  const int lslot = lane & 7;      // 16B slot within 128B row

  f32x4 acc[8][4];
#pragma unroll
  for (int i = 0; i < 8; ++i)
#pragma unroll
    for (int j = 0; j < 4; ++j) acc[i][j] = (f32x4){0.f, 0.f, 0.f, 0.f};

#pragma unroll
  for (int phase = 0; phase < 2; ++phase) {
    const bf16_t* __restrict__ Ain = phase ? B : A;
    const bf16_t* __restrict__ Wt  = phase ? W1t : W0t;
    for (int kc = 0; kc < 4; ++kc) {          // K-chunks of 64
      const int kb = kc * 64;
      // A chunk: 16 x 1KB segments (4 per wave); source slot pre-swizzled (row&7)
#pragma unroll
      for (int l = 0; l < 4; ++l) {
        int s = wave * 4 + l;
        int row = s * 8 + lrow;
        int srcc = kb + ((lslot ^ (row & 7)) << 3);
        gl_lds16(&Ain[(size_t)(rowBase + row) * 256 + srcc], &As[s * 512]);
      }
      // W chunk: 32 x 1KB segments (8 per wave)
#pragma unroll
      for (int l = 0; l < 8; ++l) {
        int s = wave * 8 + l;
        int row = s * 8 + lrow;
        int srcc = kb + ((lslot ^ (row & 7)) << 3);
        gl_lds16(&Wt[(size_t)row * 256 + srcc], &Bs[s * 512]);
      }
      __syncthreads();   // drains vmcnt(0): staged data visible
#pragma unroll
      for (int k2 = 0; k2 < 2; ++k2) {        // two K=32 sub-steps
        const int c0 = k2 * 32 + quad * 8;
        bf16x8 af[8], bfr[4];
#pragma unroll
        for (int i = 0; i < 8; ++i) {
          int ar = i * 16 + lm;
          af[i] = *reinterpret_cast<const bf16x8*>(&As[ar * 64 + (c0 ^ ((ar & 7) << 3))]);
        }
#pragma unroll
        for (int j = 0; j < 4; ++j) {
          int br = wn + j * 16 + lm;
          bfr[j] = *reinterpret_cast<const bf16x8*>(&Bs[br * 64 + (c0 ^ ((br & 7) << 3))]);
        }
#pragma unroll
        for (int i = 0; i < 8; ++i)
#pragma unroll
          for (int j = 0; j < 4; ++j)
            acc[i][j] = __builtin_amdgcn_mfma_f32_16x16x32_bf16(af[i], bfr[j], acc[i][j], 0, 0, 0);
      }
      __syncthreads();   // LDS reuse next chunk; final one guards in-place epilogue
    }
  }
  float bj[4];
#pragma unroll
  for (int j = 0; j < 4; ++j) bj[j] = bias[wn + j * 16 + lm];
#pragma unroll
  for (int i = 0; i < 8; ++i) {
#pragma unroll
    for (int j = 0; j < 4; ++j) {
      int col = wn + j * 16 + lm;
#pragma unroll
      for (int r = 0; r < 4; ++r) {
        int row = rowBase + i * 16 + quad * 4 + r;
        C[(size_t)row * 256 + col] = f2bf(fmaxf(acc[i][j][r] + bj[j], 0.f));
      }
    }
  }
}

// pair-batched GEMM1: X1[slot] = relu(AGG@wr0_e + hb@wo0_e + br0_e), e = pe + slot
// grid = (M_PAD/128, 2 slots)
__global__ __launch_bounds__(256, 2) void k_gemm1_b(
    const bf16_t* __restrict__ AGG, const bf16_t* __restrict__ hb,
    const bf16_t* __restrict__ WT, const float* __restrict__ b_rel,
    bf16_t* __restrict__ X1p, int pe) {
  int slot = blockIdx.y, e = pe + slot;
  gemm_core128(AGG, WT + (size_t)(e * 2) * 65536,
               hb, WT + (size_t)(8 + e * 2) * 65536,
               b_rel + (size_t)(e * 2) * 256,
               X1p + (size_t)slot * M_PAD * 256, blockIdx.x * 128);
}

// pair-batched GEMM2 (in-place; row-exclusive blocks + pre-write barrier make it safe)
__global__ __launch_bounds__(256, 2) void k_gemm2_b(
    const bf16_t* __restrict__ A1p, bf16_t* __restrict__ X1p,
    const bf16_t* __restrict__ WT, const float* __restrict__ b_rel, int pe) {
  int slot = blockIdx.y, e = pe + slot;
  bf16_t* Xs = X1p + (size_t)slot * M_PAD * 256;
  gemm_core128(A1p + (size_t)slot * M_PAD * 256, WT + (size_t)(e * 2 + 1) * 65536,
               Xs, WT + (size_t)(8 + e * 2 + 1) * 65536,
               b_rel + (size_t)(e * 2 + 1) * 256, Xs, blockIdx.x * 128);
}

// ---------------- CSR gather, bf16 in/out (f32 accumulate, unroll-4) ----------------
// At its L3-path floor (~106us, invariant to ILP/TLP changes r1..r8) — frozen.
__device__ __forceinline__ void gather_core(
    const int* __restrict__ row_start, const int* __restrict__ csr_src,
    const bf16_t* __restrict__ X, bf16_t* __restrict__ Cout) {
  int tid = threadIdx.x;
  int r = blockIdx.x * 8 + (tid >> 5);
  int f = (tid & 31) * 8;
  int j0 = row_start[r], j1 = row_start[r + 1];
  float a[8] = {0.f, 0.f, 0.f, 0.f, 0.f, 0.f, 0.f, 0.f};
  int j = j0;
  for (; j + 3 < j1; j += 4) {
    int s0 = csr_src[j];
    int s1 = csr_src[j + 1];
    int s2 = csr_src[j + 2];
    int s3 = csr_src[j + 3];
    bf16x8 v0 = *reinterpret_cast<const bf16x8*>(&X[(size_t)s0 * 256 + f]);
    bf16x8 v1 = *reinterpret_cast<const bf16x8*>(&X[(size_t)s1 * 256 + f]);
    bf16x8 v2 = *reinterpret_cast<const bf16x8*>(&X[(size_t)s2 * 256 + f]);
    bf16x8 v3 = *reinterpret_cast<const bf16x8*>(&X[(size_t)s3 * 256 + f]);
#pragma unroll
    for (int t = 0; t < 8; ++t) a[t] += bf2f((unsigned short)v0[t]);
#pragma unroll
    for (int t = 0; t < 8; ++t) a[t] += bf2f((unsigned short)v1[t]);
#pragma unroll
    for (int t = 0; t < 8; ++t) a[t] += bf2f((unsigned short)v2[t]);
#pragma unroll
    for (int t = 0; t < 8; ++t) a[t] += bf2f((unsigned short)v3[t]);
  }
  for (; j < j1; ++j) {
    int s = csr_src[j];
    bf16x8 v = *reinterpret_cast<const bf16x8*>(&X[(size_t)s * 256 + f]);
#pragma unroll
    for (int t = 0; t < 8; ++t) a[t] += bf2f((unsigned short)v[t]);
  }
  ushort4 lo = make_ushort4(f2bf(a[0]), f2bf(a[1]), f2bf(a[2]), f2bf(a[3]));
  ushort4 hi = make_ushort4(f2bf(a[4]), f2bf(a[5]), f2bf(a[6]), f2bf(a[7]));
  *reinterpret_cast<ushort4*>(&Cout[(size_t)r * 256 + f]) = lo;
  *reinterpret_cast<ushort4*>(&Cout[(size_t)r * 256 + f + 4]) = hi;
}

__global__ void k_gather(const int* __restrict__ row_start, const int* __restrict__ csr_src,
                         const bf16_t* __restrict__ X, bf16_t* __restrict__ Cout) {
  gather_core(row_start, csr_src, X, Cout);
}

__global__ void k_gather_b(const int* __restrict__ row_start, const int* __restrict__ csr_src,
                           const bf16_t* __restrict__ X1p, bf16_t* __restrict__ A1p) {
  size_t off = (size_t)blockIdx.y * M_PAD * 256;
  gather_core(row_start, csr_src, X1p + off, A1p + off);
}

// ---------------- numpy-faithful f32 router (r8 form) -------------------------------
// rtw1[k*RHD+l] loads are coalesced (l = lane index). Per-(node,col) arithmetic
// BIT-IDENTICAL: ascending k chain, gf-then-bias, pairwise-8 LN chains + shfl tree8,
// f64 exp. (r9's transposed-float4 variant had 1KB lane stride: 95 -> 220us. Frozen.)
__global__ __launch_bounds__(256) void k_router_np(
    const float* __restrict__ h, const int* __restrict__ batch,
    const float* __restrict__ gf, const float* __restrict__ lnn,
    const float* __restrict__ rtw1, const float* __restrict__ rtb1,
    const float* __restrict__ lng, const float* __restrict__ lnb,
    const float* __restrict__ rtw2, const float* __restrict__ rtb2,
    const float* __restrict__ centers, float* __restrict__ sw) {
  __shared__ float smem[4][1104];
  const int tid = threadIdx.x;
  const int w = tid >> 6;
  const int l = tid & 63;
  const int nbase = blockIdx.x * (4 * NPW) + w * NPW;   // grid = 3125, exact
  float* sm = smem[w];

  // stage h transposed: hT[k][nn], conflict-free b128 writes (16B lane stride)
#pragma unroll
  for (int j = 0; j < 4; ++j) {
    f32x4 v;
#pragma unroll
    for (int nn = 0; nn < NPW; ++nn)
      v[nn] = h[(size_t)(nbase + nn) * 256 + j * 64 + l];
    *reinterpret_cast<f32x4*>(&sm[(j * 64 + l) * 4]) = v;
  }
  __syncthreads();

  float acc0[NPW], acc1[NPW];
#pragma unroll
  for (int nn = 0; nn < NPW; ++nn) { acc0[nn] = 0.f; acc1[nn] = 0.f; }
#pragma unroll
  for (int j = 0; j < 4; ++j) {
#pragma unroll 16
    for (int k2 = 0; k2 < 64; ++k2) {
      int k = j * 64 + k2;
      float w0 = rtw1[k * RHD + l];
      float w1 = rtw1[k * RHD + l + 64];
      f32x4 hv = *reinterpret_cast<const f32x4*>(&sm[k * 4]);  // uniform-addr broadcast
#pragma unroll
      for (int nn = 0; nn < NPW; ++nn) {
        acc0[nn] = __fmaf_rn(hv[nn], w0, acc0[nn]);
        acc1[nn] = __fmaf_rn(hv[nn], w1, acc1[nn]);
      }
    }
  }

  float g0a = rtw1[256 * RHD + l],      g1a = rtw1[257 * RHD + l];
  float g0b = rtw1[256 * RHD + l + 64], g1b = rtw1[257 * RHD + l + 64];
  float b0 = rtb1[l], b1v = rtb1[l + 64];
  float lga = lng[l], lgb = lng[l + 64];
  float lba = lnb[l], lbb = lnb[l + 64];

  float r0[NPW], r1[NPW];
#pragma unroll
  for (int nn = 0; nn < NPW; ++nn) {
    int node = nbase + nn;
    int g = batch[node];
    float gf0 = gf[g * 2 + 0], gf1 = gf[g * 2 + 1];
    float t0 = acc0[nn], t1 = acc1[nn];
    t0 = __fmaf_rn(gf0, g0a, t0);
    t0 = __fmaf_rn(gf1, g1a, t0);
    t1 = __fmaf_rn(gf0, g0b, t1);
    t1 = __fmaf_rn(gf1, g1b, t1);
    r0[nn] = __fadd_rn(t0, b0);
    r1[nn] = __fadd_rn(t1, b1v);
    sm[nn * SRS + l] = r0[nn];
    sm[nn * SRS + 64 + l] = r1[nn];
  }
  __syncthreads();

  // mean reduction: 32 lanes, 8 per node (same 16-term ascending chain per sub-lane)
  float aj = 0.f;
  if (l < 32) {
    const float* Sp = &sm[(l >> 3) * SRS];
    int rj = l & 7;
    aj = Sp[rj];
    for (int i = 8; i < 128; i += 8) aj = __fadd_rn(aj, Sp[i + rj]);
  }
  float mu[NPW];
#pragma unroll
  for (int nn = 0; nn < NPW; ++nn) {
    float a0 = __shfl(aj, nn * 8 + 0, 64), a1 = __shfl(aj, nn * 8 + 1, 64);
    float a2 = __shfl(aj, nn * 8 + 2, 64), a3 = __shfl(aj, nn * 8 + 3, 64);
    float a4 = __shfl(aj, nn * 8 + 4, 64), a5 = __shfl(aj, nn * 8 + 5, 64);
    float a6 = __shfl(aj, nn * 8 + 6, 64), a7 = __shfl(aj, nn * 8 + 7, 64);
    float s01 = __fadd_rn(a0, a1), s23 = __fadd_rn(a2, a3);
    float s45 = __fadd_rn(a4, a5), s67 = __fadd_rn(a6, a7);
    float t = __fadd_rn(__fadd_rn(s01, s23), __fadd_rn(s45, s67));
    mu[nn] = __fdiv_rn(t, 128.0f);
  }

  float d0[NPW], d1[NPW];
#pragma unroll
  for (int nn = 0; nn < NPW; ++nn) {
    d0[nn] = __fsub_rn(r0[nn], mu[nn]);
    d1[nn] = __fsub_rn(r1[nn], mu[nn]);
    sm[nn * SRS + l] = __fmul_rn(d0[nn], d0[nn]);
    sm[nn * SRS + 64 + l] = __fmul_rn(d1[nn], d1[nn]);
  }
  __syncthreads();

  // variance reduction (identical chain structure)
  float qj = 0.f;
  if (l < 32) {
    const float* Sp = &sm[(l >> 3) * SRS];
    int rj = l & 7;
    qj = Sp[rj];
    for (int i = 8; i < 128; i += 8) qj = __fadd_rn(qj, Sp[i + rj]);
  }
#pragma unroll
  for (int nn = 0; nn < NPW; ++nn) {
    float a0 = __shfl(qj, nn * 8 + 0, 64), a1 = __shfl(qj, nn * 8 + 1, 64);
    float a2 = __shfl(qj, nn * 8 + 2, 64), a3 = __shfl(qj, nn * 8 + 3, 64);
    float a4 = __shfl(qj, nn * 8 + 4, 64), a5 = __shfl(qj, nn * 8 + 5, 64);
    float a6 = __shfl(qj, nn * 8 + 6, 64), a7 = __shfl(qj, nn * 8 + 7, 64);
    float s01 = __fadd_rn(a0, a1), s23 = __fadd_rn(a2, a3);
    float s45 = __fadd_rn(a4, a5), s67 = __fadd_rn(a6, a7);
    float t = __fadd_rn(__fadd_rn(s01, s23), __fadd_rn(s45, s67));
    float var = __fdiv_rn(t, 128.0f);
    float inv = __fdiv_rn(1.0f, sqrtf(__fadd_rn(var, 1e-5f)));
    float y0 = __fadd_rn(__fmul_rn(__fmul_rn(d0[nn], inv), lga), lba);
    float y1 = __fadd_rn(__fmul_rn(__fmul_rn(d1[nn], inv), lgb), lbb);
    sm[544 + nn * SRS + l] = fmaxf(y0, 0.f);
    sm[544 + nn * SRS + 64 + l] = fmaxf(y1, 0.f);
  }
  __syncthreads();

  // head: 16 lanes = 4 nodes x 4 cols, same serial 128-FMA ascending chain per col
  if (l < 16) {
    int nn = l >> 2, c = l & 3;
    int node = nbase + nn;
    const float* Ap = &sm[544 + nn * SRS];
    float acc = 0.f;
    for (int k = 0; k < 128; ++k) acc = __fmaf_rn(Ap[k], rtw2[k * 4 + c], acc);
    float lrn = __fadd_rn(acc, rtb2[c]);
    float nl = lnn[batch[node]];
    float dd = __fsub_rn(nl, centers[c]);
    float pr = -__fmul_rn(dd, dd);
    sm[1088 + nn * 4 + c] = __fadd_rn(__fmul_rn(0.65f, lrn), __fmul_rn(0.35f, pr));
  }
  __syncthreads();

  // softmax + top2: 4 lanes = 4 nodes (identical code to l==0 path)
  if (l < NPW) {
    int nn = l;
    int node = nbase + nn;
    float lg[4] = {sm[1088 + nn * 4 + 0], sm[1088 + nn * 4 + 1],
                   sm[1088 + nn * 4 + 2], sm[1088 + nn * 4 + 3]};
    float mx = fmaxf(fmaxf(lg[0], lg[1]), fmaxf(lg[2], lg[3]));
    float e[4];
#pragma unroll
    for (int c = 0; c < 4; ++c)
      e[c] = (float)exp((double)__fsub_rn(lg[c], mx));
    float S = __fadd_rn(__fadd_rn(__fadd_rn(e[0], e[1]), e[2]), e[3]);
    float p[4];
#pragma unroll
    for (int c = 0; c < 4; ++c) p[c] = __fdiv_rn(e[c], S);
    int i1 = 0;
#pragma unroll
    for (int c = 1; c < 4; ++c) if (p[c] > p[i1]) i1 = c;
    int i2 = -1;
#pragma unroll
    for (int c = 0; c < 4; ++c) {
      if (c == i1) continue;
      if (i2 < 0 || p[c] > p[i2]) i2 = c;
    }
    float den = __fadd_rn(__fadd_rn(p[i1], p[i2]), 1e-8f);
    float swv[4] = {0.f, 0.f, 0.f, 0.f};
    swv[i1] = __fdiv_rn(p[i1], den);
    swv[i2] = __fdiv_rn(p[i2], den);
    *reinterpret_cast<float4*>(&sw[node * 4]) =
        make_float4(swv[0], swv[1], swv[2], swv[3]);
  }
}

// ---------------- head stage 1 (pair-batched): packed Pp/Qp[n][e*8+c] ---------------
// P (gatherable) and Q (root) stored e-major packed 32-float rows so the headfin
// gather reads one contiguous 128B row per edge. Same computed values as r8.
__global__ void k_headPQ_b(const bf16_t* __restrict__ X2p,
                           const float* __restrict__ w_relo, const float* __restrict__ w_rooto,
                           float* __restrict__ Pp, float* __restrict__ Qp, int pe) {
  int slot = blockIdx.y, e = pe + slot;
  const bf16_t* X2 = X2p + (size_t)slot * M_PAD * 256;
  const float* wro = w_relo + (size_t)e * 256 * OUTD;
  const float* wto = w_rooto + (size_t)e * 256 * OUTD;
  int tid = threadIdx.x;
  int r = blockIdx.x * 4 + (tid >> 6);    // grid.x = N/4 exact
  int lane = tid & 63;
  int k0 = lane * 4;
  float wr_[24], wt_[24];
#pragma unroll
  for (int q = 0; q < 6; ++q) {
    float4 a = *reinterpret_cast<const float4*>(&wro[k0 * 6 + q * 4]);
    wr_[q * 4 + 0] = a.x; wr_[q * 4 + 1] = a.y; wr_[q * 4 + 2] = a.z; wr_[q * 4 + 3] = a.w;
    float4 b = *reinterpret_cast<const float4*>(&wto[k0 * 6 + q * 4]);
    wt_[q * 4 + 0] = b.x; wt_[q * 4 + 1] = b.y; wt_[q * 4 + 2] = b.z; wt_[q * 4 + 3] = b.w;
  }
  ushort4 xv4 = *reinterpret_cast<const ushort4*>(&X2[(size_t)r * 256 + k0]);
  float xv[4] = {bf2f(xv4.x), bf2f(xv4.y), bf2f(xv4.z), bf2f(xv4.w)};
  float p[12] = {0.f, 0.f, 0.f, 0.f, 0.f, 0.f, 0.f, 0.f, 0.f, 0.f, 0.f, 0.f};
#pragma unroll
  for (int jj = 0; jj < 4; ++jj)
#pragma unroll
    for (int c = 0; c < 6; ++c) {
      p[c]     += xv[jj] * wr_[jj * 6 + c];
      p[6 + c] += xv[jj] * wt_[jj * 6 + c];
    }
#pragma unroll
  for (int off = 32; off > 0; off >>= 1)
#pragma unroll
    for (int c = 0; c < 12; ++c) p[c] += __shfl_down(p[c], off, 64);
  if (lane == 0) {
#pragma unroll
    for (int c = 0; c < 6; ++c) {
      Pp[(size_t)r * 32 + e * 8 + c] = p[c];
      Qp[(size_t)r * 32 + e * 8 + c] = p[6 + c];
    }
  }
}

// ---------------- head stage 2: gather-style over packed Pp ------------------------
// 32 lanes per dst row, each lane owns one (e,c) slot; per edge the half-wave reads
// one contiguous 128B Pp row. Per-(e,c) add chain ascending-j; final combine
// expression shape identical to r8 -> bit-identical output.
__global__ void k_headfin_all(const int* __restrict__ row_start,
                              const int* __restrict__ csr_src,
                              const float* __restrict__ Pp, const float* __restrict__ Qp,
                              const float* __restrict__ b_relo,
                              const float* __restrict__ sw, float* __restrict__ out) {
  int tid = threadIdx.x;
  int r = blockIdx.x * 8 + (tid >> 5);    // grid = N/8 exact
  int l32 = tid & 31;
  int e = l32 >> 3, c = l32 & 7;
  int j0 = row_start[r], j1 = row_start[r + 1];
  float av = 0.f;
  int j = j0;
  for (; j + 3 < j1; j += 4) {
    int s0 = csr_src[j];
    int s1 = csr_src[j + 1];
    int s2 = csr_src[j + 2];
    int s3 = csr_src[j + 3];
    float v0 = Pp[(size_t)s0 * 32 + l32];
    float v1 = Pp[(size_t)s1 * 32 + l32];
    float v2 = Pp[(size_t)s2 * 32 + l32];
    float v3 = Pp[(size_t)s3 * 32 + l32];
    av += v0; av += v1; av += v2; av += v3;
  }
  for (; j < j1; ++j) av += Pp[(size_t)csr_src[j] * 32 + l32];
  float q = Qp[(size_t)r * 32 + l32];
  float b = (c < 6) ? b_relo[e * 6 + c] : 0.f;
  float t = av + b + q;
  int base = tid & 32;                   // wave-half origin
  float t0 = __shfl(t, base + c, 64);
  float t1 = __shfl(t, base + 8 + c, 64);
  float t2 = __shfl(t, base + 16 + c, 64);
  float t3 = __shfl(t, base + 24 + c, 64);
  if (e == 0 && c < 6) {
    float4 s4 = *reinterpret_cast<const float4*>(&sw[r * 4]);
    float v = s4.x * t0;
    v += s4.y * t1;
    v += s4.z * t2;
    v += s4.w * t3;
    out[r * 6 + c] = v;
  }
}

// ---------------- launch ----------------
extern "C" void kernel_launch(void* const* d_in, const int* in_sizes, int n_in,
                              void* d_out, int out_size, void* d_ws, size_t ws_size,
                              hipStream_t stream) {
  const float* x        = (const float*)d_in[0];
  const int*   edge     = (const int*)d_in[1];
  const int*   batch    = (const int*)d_in[2];
  const float* enc_w1   = (const float*)d_in[4];
  const float* enc_b1   = (const float*)d_in[5];
  const float* enc_w2   = (const float*)d_in[6];
  const float* enc_b2   = (const float*)d_in[7];
  const float* rt_w1    = (const float*)d_in[8];
  const float* rt_b1    = (const float*)d_in[9];
  const float* ln_g     = (const float*)d_in[10];
  const float* ln_b     = (const float*)d_in[11];
  const float* rt_w2    = (const float*)d_in[12];
  const float* rt_b2    = (const float*)d_in[13];
  const float* centers  = (const float*)d_in[14];
  const float* w_rel    = (const float*)d_in[15];
  const float* b_rel    = (const float*)d_in[16];
  const float* w_root   = (const float*)d_in[17];
  const float* w_relo   = (const float*)d_in[18];
  const float* b_relo   = (const float*)d_in[19];
  const float* w_rooto  = (const float*)d_in[20];
  float* out = (float*)d_out;

  char* wsp = (char*)d_ws;
  auto alloc = [&](size_t bytes) -> char* {
    char* p = wsp;
    wsp += (bytes + 255) & ~(size_t)255;
    return p;
  };
  const size_t actF32 = (size_t)M_PAD * 256 * sizeof(float);    // 51.25 MB
  const size_t actB16 = (size_t)M_PAD * 256 * sizeof(bf16_t);   // 25.63 MB
  char*   hx  = alloc(actF32);    // h; doubles as X1/X2 pair after router
  float*  h   = (float*)hx;
  bf16_t* X1p = (bf16_t*)hx;
  char*   tx  = alloc(actF32);    // t; doubles as A1 pair after encoder GEMM
  float*  t   = (float*)tx;
  bf16_t* A1p = (bf16_t*)tx;
  bf16_t* hb  = (bf16_t*)alloc(actB16);
  bf16_t* AGG = (bf16_t*)alloc(actB16);
  bf16_t* WT  = (bf16_t*)alloc((size_t)16 * 65536 * sizeof(bf16_t));
  float* Pp   = (float*)alloc((size_t)N_NODES * 32 * sizeof(float));   // 6.4 MB
  float* Qp   = (float*)alloc((size_t)N_NODES * 32 * sizeof(float));   // 6.4 MB
  float* swp  = (float*)alloc((size_t)N_NODES * 4 * sizeof(float));
  int*   n_cnt = (int*)alloc(NG * sizeof(int));
  int*   e_cnt = (int*)alloc(NG * sizeof(int));
  float* gfbuf = (float*)alloc(NG * 2 * sizeof(float));
  float* lnn   = (float*)alloc(NG * sizeof(float));
  int* deg       = (int*)alloc((size_t)N_NODES * sizeof(int));
  int* row_start = (int*)alloc((size_t)(N_NODES + 1) * sizeof(int));
  int* cursor    = (int*)alloc((size_t)N_NODES * sizeof(int));
  int* excl      = (int*)alloc((size_t)N_NODES * sizeof(int));
  int* bsum      = (int*)alloc(SCAN_BLK * sizeof(int));
  int* boff      = (int*)alloc(SCAN_BLK * sizeof(int));
  int* csr_src   = (int*)alloc((size_t)NUM_EDGES * sizeof(int));

  // graph stats + CSR build + weight prep
  k_zero<<<(N_NODES + 255) / 256, 256, 0, stream>>>(deg, n_cnt, e_cnt);
  k_count<<<(NUM_EDGES + 255) / 256, 256, 0, stream>>>(batch, edge, n_cnt, e_cnt, deg);
  k_graph_stats<<<1, 64, 0, stream>>>(n_cnt, e_cnt, gfbuf, lnn);
  k_scan_a<<<SCAN_BLK, 256, 0, stream>>>(deg, excl, bsum);
  k_scan_b<<<1, 256, 0, stream>>>(bsum, boff, row_start);
  k_scan_c<<<SCAN_BLK, 256, 0, stream>>>(excl, boff, row_start, cursor);
  k_fill<<<(NUM_EDGES + 255) / 256, 256, 0, stream>>>(edge, cursor, csr_src);
  dim3 wgrid(16, 4);
  k_wprep<<<wgrid, 256, 0, stream>>>(w_rel, w_root, WT);

  // encoder (frozen math; epilogue also writes hb)
  k_enc1<<<(N_NODES + 15) / 16, 256, 0, stream>>>(x, enc_w1, enc_b1, t);
  dim3 egrid(M_PAD / 128, 2);
  k_gemm_enc<<<egrid, 256, 0, stream>>>(t, enc_w2, enc_b2, h, hb, N_NODES);

  // router (r8 form: coalesced scalar weight loads; bit-identical arithmetic)
  k_router_np<<<N_NODES / (4 * NPW), 256, 0, stream>>>(
      h, batch, gfbuf, lnn, rt_w1, rt_b1, ln_g, ln_b, rt_w2, rt_b2, centers, swp);

  // loop-invariant agg_h (after router: X1p will overwrite h)
  k_gather<<<N_NODES / 8, 256, 0, stream>>>(row_start, csr_src, hb, AGG);

  // experts, pair-batched (GEMMs: 128 rows/block, global_load_lds, grid.y = slot)
  dim3 ggrid(M_PAD / 128, 2);
  dim3 grid_gather(N_NODES / 8, 2);
  dim3 grid_pq(N_NODES / 4, 2);
  for (int pe = 0; pe < NEXP; pe += 2) {
    k_gemm1_b<<<ggrid, 256, 0, stream>>>(AGG, hb, WT, b_rel, X1p, pe);
    k_gather_b<<<grid_gather, 256, 0, stream>>>(row_start, csr_src, X1p, A1p);
    k_gemm2_b<<<ggrid, 256, 0, stream>>>(A1p, X1p, WT, b_rel, pe);
    k_headPQ_b<<<grid_pq, 256, 0, stream>>>(X1p, w_relo, w_rooto, Pp, Qp, pe);
  }
  k_headfin_all<<<N_NODES / 8, 256, 0, stream>>>(
      row_start, csr_src, Pp, Qp, b_relo, swp, out);
}